// Round 13
// baseline (1512.333 us; speedup 1.0000x reference)
//
#include <hip/hip_runtime.h>

constexpr int H    = 128;
constexpr int LNUM = 5;
constexpr int NG   = 512;
constexpr int EMB  = 640;   // LNUM * H
constexpr float BN_EPS = 1e-5f;

typedef __attribute__((ext_vector_type(8))) short bf16x8;
typedef __attribute__((ext_vector_type(4))) float f32x4;

__device__ inline unsigned short f2bf(float f){
  unsigned u = __builtin_bit_cast(unsigned, f);
  u += 0x7FFF + ((u >> 16) & 1);
  return (unsigned short)(u >> 16);
}
__device__ inline float bf2f(unsigned short h){
  unsigned u = ((unsigned)h) << 16;
  return __builtin_bit_cast(float, u);
}

// bijective XCD chunk swizzle (m204)
__device__ inline int xcd_swz(int bid, int nwg){
  int q = nwg >> 3, r = nwg & 7;
  int xcd = bid & 7, idx = bid >> 3;
  return (xcd < r ? xcd*(q+1) : r*(q+1) + (xcd-r)*q) + idx;
}

// ---------------- utility ----------------
__global__ void k_zeroi(int* p, int n){
  int i = blockIdx.x*256 + threadIdx.x;
  if (i < n) p[i] = 0;
}

// ---------------- CSR build ----------------
__global__ void k_hist(const int* __restrict__ dst, int E, int* deg){
  int e = blockIdx.x*256 + threadIdx.x;
  if (e < E) atomicAdd(&deg[dst[e]], 1);
}

__global__ __launch_bounds__(1024) void k_scan(int* degcur, int* __restrict__ rowptr, int n){
  __shared__ int wsum[16];
  __shared__ int carry;
  int tid = threadIdx.x, wid = tid >> 6, lane = tid & 63;
  if (tid == 0){ carry = 0; rowptr[0] = 0; }
  __syncthreads();
  for (int base = 0; base < n; base += 1024){
    int v = (base + tid < n) ? degcur[base + tid] : 0;
    int s = v;
#pragma unroll
    for (int off = 1; off < 64; off <<= 1){
      int t = __shfl_up(s, off);
      if (lane >= off) s += t;
    }
    if (lane == 63) wsum[wid] = s;
    __syncthreads();
    if (wid == 0 && lane < 16){
      int wv = wsum[lane];
#pragma unroll
      for (int off = 1; off < 16; off <<= 1){
        int t = __shfl_up(wv, off);
        if (lane >= off) wv += t;
      }
      wsum[lane] = wv;
    }
    __syncthreads();
    int incl = s + (wid ? wsum[wid-1] : 0) + carry;
    if (base + tid < n){ rowptr[base + tid + 1] = incl; degcur[base + tid] = incl - v; }
    __syncthreads();
    if (tid == 0) carry += wsum[15];
    __syncthreads();
  }
}

__global__ void k_scatter(const int* __restrict__ src, const int* __restrict__ dst,
                          int E, int* cursor, int* __restrict__ colsrc){
  int e = blockIdx.x*256 + threadIdx.x;
  if (e < E){
    int d = dst[e];
    int pos = atomicAdd(&cursor[d], 1);
    colsrc[pos] = src[e];
  }
}

// deterministic neighbor order: sort each node's segment ascending
__global__ void k_sortseg(const int* __restrict__ rowptr, int* __restrict__ colsrc, int n){
  int node = blockIdx.x*256 + threadIdx.x;
  if (node < n){
    int lo = rowptr[node], hi = rowptr[node+1];
    for (int i = lo + 1; i < hi; ++i){
      int v = colsrc[i];
      int j = i - 1;
      while (j >= lo && colsrc[j] > v){ colsrc[j+1] = colsrc[j]; --j; }
      colsrc[j+1] = v;
    }
  }
}

__global__ void k_gstart(const int* __restrict__ batch, int N, int* __restrict__ gstart){
  int g = blockIdx.x*256 + threadIdx.x;
  if (g <= NG){
    int lo = 0, hi = N;
    while (lo < hi){
      int mid = (lo + hi) >> 1;
      if (batch[mid] < g) lo = mid + 1; else hi = mid;
    }
    gstart[g] = lo;
  }
}

// ---- weight cast+transpose: W[k][n] f32 -> Wt[n][ldt] bf16 at column offset koff ----
__global__ void k_castT(const float* __restrict__ W, unsigned short* __restrict__ Wt,
                        int K, int Nn, int ldt, int koff){
  __shared__ float sh[32][33];
  const size_t in_off  = (size_t)blockIdx.z * K * Nn;
  const size_t out_off = (size_t)blockIdx.z * Nn * ldt;
  int n0 = blockIdx.x*32, k0 = blockIdx.y*32;
  int tx = threadIdx.x, ty = threadIdx.y;   // 32 x 8
  for (int r = ty; r < 32; r += 8)
    sh[r][tx] = W[in_off + (size_t)(k0 + r)*Nn + n0 + tx];
  __syncthreads();
  for (int r = ty; r < 32; r += 8)
    Wt[out_off + (size_t)(n0 + r)*ldt + koff + k0 + tx] = f2bf(sh[tx][r]);
}

__global__ void k_bias2(const float* __restrict__ a, const float* __restrict__ b,
                        float* __restrict__ o){
  int i = threadIdx.x;
  o[i] = a[i] + b[i];
}

// ---------------- pooling (applies BN2+ReLU in f32 from pre-BN2 values) ----------------
__global__ __launch_bounds__(320) void k_pool(const unsigned short* __restrict__ xpre,
                                              const float* __restrict__ bnsc2,
                                              const float* __restrict__ bnsf2,
                                              const int* __restrict__ gstart,
                                              float* __restrict__ pooled){
  int g = blockIdx.x;
  int t = threadIdx.x;              // handles feats 2t, 2t+1
  int f0 = 2*t;
  int l = f0 >> 7, c = f0 & 127;
  float sc0 = bnsc2[l*128 + c],     sf0 = bnsf2[l*128 + c];
  float sc1 = bnsc2[l*128 + c + 1], sf1 = bnsf2[l*128 + c + 1];
  int n0 = gstart[g], n1 = gstart[g+1];
  float a0 = 0.f, a1 = 0.f;
  for (int n = n0; n < n1; ++n){
    unsigned u = ((const unsigned*)xpre)[(size_t)n*(EMB/2) + t];
    a0 += fmaxf(fmaf(sc0, bf2f((unsigned short)u),        sf0), 0.f);
    a1 += fmaxf(fmaf(sc1, bf2f((unsigned short)(u >> 16)), sf1), 0.f);
  }
  *(float2*)(pooled + (size_t)g*EMB + 2*t) = make_float2(a0, a1);
}

__global__ __launch_bounds__(128) void k_pred(const float* __restrict__ pooled,
                                              const float* __restrict__ W,
                                              const float* __restrict__ b,
                                              float* __restrict__ xcat){
  int g = blockIdx.x, l = blockIdx.y, o = threadIdx.x;
  __shared__ float sh[128];
  sh[o] = pooled[(size_t)g*EMB + l*H + o];
  __syncthreads();
  const float* Wl = W + (size_t)l*H*H;
  float acc = b[l*H + o];
  for (int k = 0; k < H; ++k) acc = fmaf(sh[k], Wl[k*H + o], acc);
  xcat[(size_t)g*EMB + l*H + o] = acc;
}

// ---- bf16 MFMA GEMM, 128x128 tile, BK=64, depth-2 pipeline, RAW s_barrier ----
// (unchanged from round 10/11 — counted vmcnt(4), never drained in main loop)
template<bool RELU, bool OUT_BF16, bool DUAL>
__global__ __launch_bounds__(512) void k_mm(
    const unsigned short* __restrict__ A, int lda,
    const unsigned short* __restrict__ A2,
    const unsigned short* __restrict__ Bt, int ldb,
    const float* __restrict__ bias,
    void* __restrict__ Cv, int ldc,
    int M, int K)
{
  __shared__ union LdsU {
    unsigned short stage[2][2][8192];
    unsigned short sc16[128*136];
    float          sc32[128*132];
  } u;
  const int tid  = threadIdx.x;
  const int lane = tid & 63;
  const int w    = tid >> 6;
  const int wr   = w >> 2, wc = w & 3;

  const int nwg = gridDim.x * gridDim.y;
  const int bid = blockIdx.y * gridDim.x + blockIdx.x;
  const int wg  = xcd_swz(bid, nwg);
  const int col0 = (wg % gridDim.x) * 128;
  const int row0 = (wg / gridDim.x) * 128;
  const int KA   = DUAL ? (K >> 1) : K;

  const unsigned short *sA[2], *sA2p[2], *sB[2];
  int dOff[2];
#pragma unroll
  for (int j = 0; j < 2; ++j){
    int d = w*2048 + j*1024 + lane*16;
    int m = d >> 7;
    int inner = (d & 127) ^ ((m & 7) << 4);
    int gm = row0 + m; if (gm > M-1) gm = M-1;
    sA[j]  = A + (size_t)gm*lda + (inner >> 1);
    if (DUAL) sA2p[j] = A2 + (size_t)gm*lda + (inner >> 1);
    sB[j]  = Bt + (size_t)(col0 + m)*ldb + (inner >> 1);
    dOff[j] = w*2048 + j*1024;
  }

  f32x4 acc[4][2];
#pragma unroll
  for (int i = 0; i < 4; ++i)
#pragma unroll
    for (int j = 0; j < 2; ++j)
      acc[i][j] = (f32x4){0.f, 0.f, 0.f, 0.f};

  auto STAGE = [&](int buf, int kt){
    int k0 = kt*64, ka = k0;
    bool second = DUAL && (k0 >= KA);
    if (second) ka = k0 - KA;
#pragma unroll
    for (int j = 0; j < 2; ++j){
      const unsigned short* s = second ? (sA2p[j] + ka) : (sA[j] + ka);
      __builtin_amdgcn_global_load_lds(
          (const __attribute__((address_space(1))) void*)s,
          (__attribute__((address_space(3))) void*)((char*)&u.stage[buf][0][0] + dOff[j]),
          16, 0, 0);
    }
#pragma unroll
    for (int j = 0; j < 2; ++j)
      __builtin_amdgcn_global_load_lds(
          (const __attribute__((address_space(1))) void*)(sB[j] + k0),
          (__attribute__((address_space(3))) void*)((char*)&u.stage[buf][1][0] + dOff[j]),
          16, 0, 0);
  };

  const int NT = K / 64;
  STAGE(0, 0);
  STAGE(1, 1);
  asm volatile("s_waitcnt vmcnt(4)" ::: "memory");
  asm volatile("s_barrier" ::: "memory");

  for (int t = 0; t < NT; ++t){
    const char* Ab = (const char*)&u.stage[t & 1][0][0];
    const char* Bb = (const char*)&u.stage[t & 1][1][0];
    bf16x8 af[2][4], bq[2][2];
#pragma unroll
    for (int kk = 0; kk < 2; ++kk){
      const int kb = kk*64 + ((lane >> 4) << 4);
#pragma unroll
      for (int i = 0; i < 4; ++i){
        int row = wr*64 + i*16 + (lane & 15);
        af[kk][i] = *(const bf16x8*)(Ab + ((row*128 + kb) ^ ((row & 7) << 4)));
      }
#pragma unroll
      for (int j = 0; j < 2; ++j){
        int col = wc*32 + j*16 + (lane & 15);
        bq[kk][j] = *(const bf16x8*)(Bb + ((col*128 + kb) ^ ((col & 7) << 4)));
      }
    }
    if (t + 2 < NT){
      asm volatile("s_barrier" ::: "memory");
      STAGE(t & 1, t + 2);
    }
#pragma unroll
    for (int kk = 0; kk < 2; ++kk)
#pragma unroll
      for (int i = 0; i < 4; ++i)
#pragma unroll
        for (int j = 0; j < 2; ++j)
          acc[i][j] = __builtin_amdgcn_mfma_f32_16x16x32_bf16(af[kk][i], bq[kk][j], acc[i][j], 0, 0, 0);
    if (t + 1 < NT){
      if (t + 2 < NT) asm volatile("s_waitcnt vmcnt(4)" ::: "memory");
      else            asm volatile("s_waitcnt vmcnt(0)" ::: "memory");
      asm volatile("s_barrier" ::: "memory");
    }
  }

  __syncthreads();
  if (OUT_BF16){
#pragma unroll
    for (int j = 0; j < 2; ++j){
      int cl = wc*32 + j*16 + (lane & 15);
      float bs = bias[col0 + cl];
#pragma unroll
      for (int i = 0; i < 4; ++i){
        int rb = wr*64 + i*16 + ((lane >> 4) << 2);
#pragma unroll
        for (int r = 0; r < 4; ++r){
          float v = acc[i][j][r] + bs;
          if (RELU) v = fmaxf(v, 0.f);
          u.sc16[(rb + r)*136 + cl] = f2bf(v);
        }
      }
    }
    __syncthreads();
    unsigned short* Cb = (unsigned short*)Cv;
    for (int idx = tid; idx < 128*16; idx += 512){
      int rr = idx >> 4, seg = idx & 15;
      int grow = row0 + rr;
      if (grow < M){
        uint4 vv = *(const uint4*)&u.sc16[rr*136 + seg*8];
        *(uint4*)(Cb + (size_t)grow*ldc + col0 + seg*8) = vv;
      }
    }
  } else {
#pragma unroll
    for (int j = 0; j < 2; ++j){
      int cl = wc*32 + j*16 + (lane & 15);
      float bs = bias[col0 + cl];
#pragma unroll
      for (int i = 0; i < 4; ++i){
        int rb = wr*64 + i*16 + ((lane >> 4) << 2);
#pragma unroll
        for (int r = 0; r < 4; ++r){
          float v = acc[i][j][r] + bs;
          if (RELU) v = fmaxf(v, 0.f);
          u.sc32[(rb + r)*132 + cl] = v;
        }
      }
    }
    __syncthreads();
    float* Cf = (float*)Cv;
    for (int idx = tid; idx < 128*32; idx += 512){
      int rr = idx >> 5, seg = idx & 31;
      int grow = row0 + rr;
      if (grow < M){
        float4 vv = *(const float4*)&u.sc32[rr*132 + seg*4];
        *(float4*)(Cf + (size_t)grow*ldc + col0 + seg*4) = vv;
      }
    }
  }
}

// ------- fused GIN-aggregate + conv GEMM1 + deterministic block stats -------
// Wave-per-node gather; per-block stats written (no atomics) to pa[wg][256].
template<bool IN_BF16>
__global__ __launch_bounds__(512) void k_mmca(
    const void* __restrict__ hin, int ldh,
    const int* __restrict__ rowptr, const int* __restrict__ colsrc,
    const float* __restrict__ epsp,
    const unsigned short* __restrict__ Bt,
    const float* __restrict__ bias,
    unsigned short* __restrict__ C, int ldc,
    float* __restrict__ pa,
    int M)
{
  __shared__ unsigned short shm[2*128*128];
  __shared__ float sbs[2][128], sbq[2][128];
  unsigned short* As = shm;
  unsigned short* Bs = shm + 16384;
  const int tid  = threadIdx.x;
  const int lane = tid & 63;
  const int w    = tid >> 6;
  const int wr   = w >> 2, wc = w & 3;

  const int wg   = xcd_swz(blockIdx.x, gridDim.x);
  const int row0 = wg * 128;

#pragma unroll
  for (int j = 0; j < 4; ++j){
    int d = w*4096 + j*1024 + lane*16;
    int m = d >> 8;
    int inner = (d & 255) ^ ((m & 15) << 4);
    __builtin_amdgcn_global_load_lds(
        (const __attribute__((address_space(1))) void*)(Bt + (size_t)m*H + (inner >> 1)),
        (__attribute__((address_space(3))) void*)((char*)Bs + w*4096 + j*1024),
        16, 0, 0);
  }

  // gather A: wave w owns rows [w*16, w*16+16); lane covers cols 2*lane, 2*lane+1
  {
    const int ld2 = ldh >> 1;
    float ep = 1.0f + *epsp;
    for (int rr = 0; rr < 16; ++rr){
      int r = w*16 + rr;
      int node = row0 + r; if (node > M-1) node = M-1;
      float a0, a1;
      if (IN_BF16){
        unsigned v = ((const unsigned*)hin)[(size_t)node*ld2 + lane];
        a0 = ep*bf2f((unsigned short)v); a1 = ep*bf2f((unsigned short)(v >> 16));
      } else {
        float2 f = ((const float2*)hin)[(size_t)node*ld2 + lane];
        a0 = ep*f.x; a1 = ep*f.y;
      }
      int e = rowptr[node], e1 = rowptr[node+1];
      for (; e + 2 <= e1; e += 2){
        int s0 = colsrc[e], s1 = colsrc[e+1];
        if (IN_BF16){
          unsigned v0 = ((const unsigned*)hin)[(size_t)s0*ld2 + lane];
          unsigned v1 = ((const unsigned*)hin)[(size_t)s1*ld2 + lane];
          a0 += bf2f((unsigned short)v0) + bf2f((unsigned short)v1);
          a1 += bf2f((unsigned short)(v0 >> 16)) + bf2f((unsigned short)(v1 >> 16));
        } else {
          float2 f0 = ((const float2*)hin)[(size_t)s0*ld2 + lane];
          float2 f1 = ((const float2*)hin)[(size_t)s1*ld2 + lane];
          a0 += f0.x + f1.x; a1 += f0.y + f1.y;
        }
      }
      for (; e < e1; ++e){
        int s = colsrc[e];
        if (IN_BF16){
          unsigned v = ((const unsigned*)hin)[(size_t)s*ld2 + lane];
          a0 += bf2f((unsigned short)v); a1 += bf2f((unsigned short)(v >> 16));
        } else {
          float2 f = ((const float2*)hin)[(size_t)s*ld2 + lane];
          a0 += f.x; a1 += f.y;
        }
      }
      unsigned pk = (unsigned)f2bf(a0) | ((unsigned)f2bf(a1) << 16);
      int byte = (r*256 + lane*4) ^ ((r & 15) << 4);
      *(unsigned*)((char*)As + byte) = pk;
    }
  }

  asm volatile("s_waitcnt vmcnt(0)" ::: "memory");
  __syncthreads();

  f32x4 acc[4][2];
#pragma unroll
  for (int i = 0; i < 4; ++i)
#pragma unroll
    for (int j = 0; j < 2; ++j)
      acc[i][j] = (f32x4){0.f, 0.f, 0.f, 0.f};

#pragma unroll
  for (int kk = 0; kk < 4; ++kk){
    const int kb = kk*64 + ((lane >> 4) << 4);
    bf16x8 af[4], bfr[2];
#pragma unroll
    for (int i = 0; i < 4; ++i){
      int row = wr*64 + i*16 + (lane & 15);
      af[i] = *(const bf16x8*)((const char*)As + ((row*256 + kb) ^ ((row & 15) << 4)));
    }
#pragma unroll
    for (int j = 0; j < 2; ++j){
      int col = wc*32 + j*16 + (lane & 15);
      bfr[j] = *(const bf16x8*)((const char*)Bs + ((col*256 + kb) ^ ((col & 15) << 4)));
    }
#pragma unroll
    for (int i = 0; i < 4; ++i)
#pragma unroll
      for (int j = 0; j < 2; ++j)
        acc[i][j] = __builtin_amdgcn_mfma_f32_16x16x32_bf16(af[i], bfr[j], acc[i][j], 0, 0, 0);
  }

  // deterministic block stats: wave partials -> LDS -> single combine
#pragma unroll
  for (int j = 0; j < 2; ++j){
    int col = wc*32 + j*16 + (lane & 15);
    float bs = bias[col];
    float s = 0.f, q = 0.f;
#pragma unroll
    for (int i = 0; i < 4; ++i){
      int rb = row0 + wr*64 + i*16 + ((lane >> 4) << 2);
#pragma unroll
      for (int r = 0; r < 4; ++r){
        if (rb + r < M){
          float v = acc[i][j][r] + bs;
          s += v; q += v*v;
        }
      }
    }
    s += __shfl_xor(s, 16); q += __shfl_xor(q, 16);
    s += __shfl_xor(s, 32); q += __shfl_xor(q, 32);
    if (lane < 16){ sbs[wr][col] = s; sbq[wr][col] = q; }
  }
  __syncthreads();
  if (tid < 128){
    pa[(size_t)wg*256 + tid]       = sbs[0][tid] + sbs[1][tid];
    pa[(size_t)wg*256 + 128 + tid] = sbq[0][tid] + sbq[1][tid];
  }

  // epilogue: transpose via LDS, coalesced 16-B stores
  __syncthreads();
#pragma unroll
  for (int j = 0; j < 2; ++j){
    int cl = wc*32 + j*16 + (lane & 15);
    float bs = bias[cl];
#pragma unroll
    for (int i = 0; i < 4; ++i){
      int rb = wr*64 + i*16 + ((lane >> 4) << 2);
#pragma unroll
      for (int r = 0; r < 4; ++r)
        shm[(rb + r)*136 + cl] = f2bf(acc[i][j][r] + bs);
    }
  }
  __syncthreads();
  for (int idx = tid; idx < 128*16; idx += 512){
    int rr = idx >> 4, seg = idx & 15;
    int grow = row0 + rr;
    if (grow < M){
      uint4 vv = *(const uint4*)&shm[rr*136 + seg*8];
      *(uint4*)(C + (size_t)grow*ldc + seg*8) = vv;
    }
  }
}

// ------- conv GEMM2: deterministic pa-reduction BN1 on A + block stats to pb -------
__global__ __launch_bounds__(512) void k_mmc2(
    const unsigned short* __restrict__ A,     // [M][128] bf16 (pre-BN1)
    const unsigned short* __restrict__ Bt,
    const float* __restrict__ bias,
    const float* __restrict__ pa,             // [nwg][256] BN1 partials
    const float* __restrict__ g1, const float* __restrict__ be1,
    float invn,
    unsigned short* __restrict__ C, int ldc,
    float* __restrict__ pb,                   // [nwg][256] BN2 partials
    int M)
{
  __shared__ unsigned short shm[2*128*128];
  __shared__ float bnsc[128], bnsf[128];
  __shared__ float rs[4][128], rq[4][128];
  unsigned short* As = shm;
  unsigned short* Bs = shm + 16384;
  const int tid  = threadIdx.x;
  const int lane = tid & 63;
  const int w    = tid >> 6;
  const int wr   = w >> 2, wc = w & 3;
  const int nwg  = gridDim.x;

  const int wg   = xcd_swz(blockIdx.x, nwg);
  const int row0 = wg * 128;

#pragma unroll
  for (int j = 0; j < 4; ++j){
    int d = w*4096 + j*1024 + lane*16;
    int m = d >> 8;
    int inner = (d & 255) ^ ((m & 15) << 4);
    int gm = row0 + m; if (gm > M-1) gm = M-1;
    __builtin_amdgcn_global_load_lds(
        (const __attribute__((address_space(1))) void*)(A + (size_t)gm*H + (inner >> 1)),
        (__attribute__((address_space(3))) void*)((char*)As + w*4096 + j*1024),
        16, 0, 0);
    __builtin_amdgcn_global_load_lds(
        (const __attribute__((address_space(1))) void*)(Bt + (size_t)m*H + (inner >> 1)),
        (__attribute__((address_space(3))) void*)((char*)Bs + w*4096 + j*1024),
        16, 0, 0);
  }

  // deterministic BN1 finalize: fixed-partition reduction of pa (under staging wait)
  {
    int c = tid & 127, part = tid >> 7;     // 4 partitions
    float s = 0.f, q = 0.f;
    for (int bi = part; bi < nwg; bi += 4){
      s += pa[(size_t)bi*256 + c];
      q += pa[(size_t)bi*256 + 128 + c];
    }
    rs[part][c] = s; rq[part][c] = q;
  }
  __syncthreads();
  if (tid < 128){
    float s = rs[0][tid] + rs[1][tid] + rs[2][tid] + rs[3][tid];
    float q = rq[0][tid] + rq[1][tid] + rq[2][tid] + rq[3][tid];
    float m = s*invn;
    float v = q*invn - m*m;
    float inv = rsqrtf(v + BN_EPS);
    float sc = g1[tid]*inv;
    bnsc[tid] = sc;
    bnsf[tid] = be1[tid] - m*sc;
  }

  asm volatile("s_waitcnt vmcnt(0)" ::: "memory");
  __syncthreads();

  f32x4 acc[4][2];
#pragma unroll
  for (int i = 0; i < 4; ++i)
#pragma unroll
    for (int j = 0; j < 2; ++j)
      acc[i][j] = (f32x4){0.f, 0.f, 0.f, 0.f};

#pragma unroll
  for (int kk = 0; kk < 4; ++kk){
    const int kb = kk*64 + ((lane >> 4) << 4);
    bf16x8 af[4], bfr[2];
#pragma unroll
    for (int i = 0; i < 4; ++i){
      int row = wr*64 + i*16 + (lane & 15);
      af[i] = *(const bf16x8*)((const char*)As + ((row*256 + kb) ^ ((row & 15) << 4)));
    }
#pragma unroll
    for (int j = 0; j < 2; ++j){
      int col = wc*32 + j*16 + (lane & 15);
      bfr[j] = *(const bf16x8*)((const char*)Bs + ((col*256 + kb) ^ ((col & 15) << 4)));
    }
    {
      int k8 = kk*32 + ((lane >> 4) << 3);
      float4 s0 = *(const float4*)(&bnsc[k8]), s1 = *(const float4*)(&bnsc[k8 + 4]);
      float4 f0 = *(const float4*)(&bnsf[k8]), f1 = *(const float4*)(&bnsf[k8 + 4]);
      float sc[8] = {s0.x,s0.y,s0.z,s0.w,s1.x,s1.y,s1.z,s1.w};
      float sf[8] = {f0.x,f0.y,f0.z,f0.w,f1.x,f1.y,f1.z,f1.w};
#pragma unroll
      for (int i = 0; i < 4; ++i){
        bf16x8 aa = af[i], o;
#pragma unroll
        for (int jj = 0; jj < 8; ++jj){
          float v = fmaxf(fmaf(sc[jj], bf2f((unsigned short)aa[jj]), sf[jj]), 0.f);
          o[jj] = (short)f2bf(v);
        }
        af[i] = o;
      }
    }
#pragma unroll
    for (int i = 0; i < 4; ++i)
#pragma unroll
      for (int j = 0; j < 2; ++j)
        acc[i][j] = __builtin_amdgcn_mfma_f32_16x16x32_bf16(af[i], bfr[j], acc[i][j], 0, 0, 0);
  }

  // deterministic block stats -> pb
  __syncthreads();   // rs/rq reuse barrier (also separates bnsc reads)
#pragma unroll
  for (int j = 0; j < 2; ++j){
    int col = wc*32 + j*16 + (lane & 15);
    float bs = bias[col];
    float s = 0.f, q = 0.f;
#pragma unroll
    for (int i = 0; i < 4; ++i){
      int rb = row0 + wr*64 + i*16 + ((lane >> 4) << 2);
#pragma unroll
      for (int r = 0; r < 4; ++r){
        if (rb + r < M){
          float v = acc[i][j][r] + bs;
          s += v; q += v*v;
        }
      }
    }
    s += __shfl_xor(s, 16); q += __shfl_xor(q, 16);
    s += __shfl_xor(s, 32); q += __shfl_xor(q, 32);
    if (lane < 16){ rs[wr][col] = s; rq[wr][col] = q; }
  }
  __syncthreads();
  if (tid < 128){
    pb[(size_t)wg*256 + tid]       = rs[0][tid] + rs[1][tid];
    pb[(size_t)wg*256 + 128 + tid] = rq[0][tid] + rq[1][tid];
  }

  __syncthreads();
#pragma unroll
  for (int j = 0; j < 2; ++j){
    int cl = wc*32 + j*16 + (lane & 15);
    float bs = bias[cl];
#pragma unroll
    for (int i = 0; i < 4; ++i){
      int rb = wr*64 + i*16 + ((lane >> 4) << 2);
#pragma unroll
      for (int r = 0; r < 4; ++r)
        shm[(rb + r)*136 + cl] = f2bf(acc[i][j][r] + bs);
    }
  }
  __syncthreads();
  for (int idx = tid; idx < 128*16; idx += 512){
    int rr = idx >> 4, seg = idx & 15;
    int grow = row0 + rr;
    if (grow < M){
      uint4 vv = *(const uint4*)&shm[rr*136 + seg*8];
      *(uint4*)(C + (size_t)grow*ldc + seg*8) = vv;
    }
  }
}

// ---- BN2 finalize: deterministic reduction of pb -> scale/shift ----
__global__ __launch_bounds__(512) void k_bnfin2(const float* __restrict__ pb,
                                                const float* __restrict__ g,
                                                const float* __restrict__ b,
                                                float* __restrict__ scale,
                                                float* __restrict__ shift,
                                                float invn, int nwg){
  __shared__ float rs[4][128], rq[4][128];
  int tid = threadIdx.x;
  int c = tid & 127, part = tid >> 7;
  float s = 0.f, q = 0.f;
  for (int bi = part; bi < nwg; bi += 4){
    s += pb[(size_t)bi*256 + c];
    q += pb[(size_t)bi*256 + 128 + c];
  }
  rs[part][c] = s; rq[part][c] = q;
  __syncthreads();
  if (tid < 128){
    float S = rs[0][tid] + rs[1][tid] + rs[2][tid] + rs[3][tid];
    float Q = rq[0][tid] + rq[1][tid] + rq[2][tid] + rq[3][tid];
    float m = S*invn;
    float v = Q*invn - m*m;
    float inv = rsqrtf(v + BN_EPS);
    float sc = g[tid]*inv;
    scale[tid] = sc;
    shift[tid] = b[tid] - m*sc;
  }
}

// ---- BN2 apply: out = bf16(relu(sc*U+sf)), U stride ldu ----
__global__ __launch_bounds__(256) void k_bnapply(const unsigned short* __restrict__ U,
                                                 int ldu,
                                                 const float* __restrict__ scale,
                                                 const float* __restrict__ shift,
                                                 unsigned short* __restrict__ out,
                                                 int ldo, int n){
  int i = blockIdx.x*256 + threadIdx.x;
  int total = n * (H/4);
  if (i < total){
    int r = i >> 5;
    int c4 = (i & 31) << 2;
    uint2 up = *(const uint2*)(U + (size_t)r*ldu + c4);
    float4 sc = *(const float4*)(scale + c4);
    float4 sf = *(const float4*)(shift + c4);
    float a = fmaxf(fmaf(sc.x, bf2f((unsigned short)up.x),       sf.x), 0.f);
    float c = fmaxf(fmaf(sc.y, bf2f((unsigned short)(up.x>>16)), sf.y), 0.f);
    float d = fmaxf(fmaf(sc.z, bf2f((unsigned short)up.y),       sf.z), 0.f);
    float e = fmaxf(fmaf(sc.w, bf2f((unsigned short)(up.y>>16)), sf.w), 0.f);
    uint2 o;
    o.x = (unsigned)f2bf(a) | ((unsigned)f2bf(c) << 16);
    o.y = (unsigned)f2bf(d) | ((unsigned)f2bf(e) << 16);
    *(uint2*)(out + (size_t)r*ldo + c4) = o;
  }
}

// ---------------- f32 GEMM 32x64 tile (graph FF, M=512) ----------------
template<bool RELU, bool ADD_D>
__global__ __launch_bounds__(256) void k_gemm64(
    const float* __restrict__ A, int lda,
    const float* __restrict__ B, int ldb,
    const float* __restrict__ bias,
    const float* D, int ldd,
    float* C, int ldc,
    int M, int N, int K)
{
  __shared__ float As[32][36];
  __shared__ float Bs[32][64];
  const int tid  = threadIdx.x;
  const int tx   = tid & 15;
  const int ty   = tid >> 4;
  const int row0 = blockIdx.x * 32;
  const int col0 = blockIdx.y * 64;
  const int am = tid >> 3;
  const int ak = (tid & 7) << 2;
  const int bk = tid >> 4;
  const int bn = (tid & 15) << 2;
  float acc[2][4] = {};

  for (int k0 = 0; k0 < K; k0 += 32){
    {
      int gr = row0 + am;
      float4 v = make_float4(0.f, 0.f, 0.f, 0.f);
      if (gr < M) v = *(const float4*)(A + (size_t)gr*lda + k0 + ak);
      As[ak+0][am]=v.x; As[ak+1][am]=v.y; As[ak+2][am]=v.z; As[ak+3][am]=v.w;
    }
#pragma unroll
    for (int h = 0; h < 2; ++h){
      int kk = bk + h*16;
      *(float4*)(&Bs[kk][bn]) = *(const float4*)(B + (size_t)(k0+kk)*ldb + col0 + bn);
    }
    __syncthreads();
#pragma unroll 8
    for (int k = 0; k < 32; ++k){
      float2 a = *(const float2*)(&As[k][ty<<1]);
      float4 b = *(const float4*)(&Bs[k][tx<<2]);
      float av[2] = {a.x, a.y};
      float bv[4] = {b.x, b.y, b.z, b.w};
#pragma unroll
      for (int i = 0; i < 2; ++i)
#pragma unroll
        for (int j = 0; j < 4; ++j)
          acc[i][j] = fmaf(av[i], bv[j], acc[i][j]);
    }
    __syncthreads();
  }

  const int col = col0 + (tx<<2);
  float4 bv = *(const float4*)(bias + col);
#pragma unroll
  for (int i = 0; i < 2; ++i){
    int row = row0 + (ty<<1) + i;
    if (row < M){
      float r[4] = {acc[i][0]+bv.x, acc[i][1]+bv.y, acc[i][2]+bv.z, acc[i][3]+bv.w};
      if (RELU){
#pragma unroll
        for (int j = 0; j < 4; ++j) r[j] = fmaxf(r[j], 0.f);
      }
      if (ADD_D){
        float4 d = *(const float4*)(D + (size_t)row*ldd + col);
        r[0]+=d.x; r[1]+=d.y; r[2]+=d.z; r[3]+=d.w;
      }
      *(float4*)(C + (size_t)row*ldc + col) = make_float4(r[0],r[1],r[2],r[3]);
    }
  }
}

// ---------------- host ----------------
extern "C" void kernel_launch(void* const* d_in, const int* in_sizes, int n_in,
                              void* d_out, int out_size, void* d_ws, size_t ws_size,
                              hipStream_t stream) {
  const float* x        = (const float*)d_in[0];
  const int*   ei       = (const int*)d_in[1];
  const int*   batch    = (const int*)d_in[2];
  const float* conv_W1  = (const float*)d_in[3];
  const float* conv_b1  = (const float*)d_in[4];
  const float* conv_g1  = (const float*)d_in[5];
  const float* conv_be1 = (const float*)d_in[6];
  const float* conv_W2  = (const float*)d_in[7];
  const float* conv_b2  = (const float*)d_in[8];
  const float* epsv     = (const float*)d_in[9];
  const float* bn_g     = (const float*)d_in[10];
  const float* bn_b     = (const float*)d_in[11];
  const float* pred_W   = (const float*)d_in[12];
  const float* pred_b   = (const float*)d_in[13];
  const float* gW       = (const float*)d_in[14];
  const float* gb       = (const float*)d_in[15];
  const float* gsW      = (const float*)d_in[16];
  const float* gsb      = (const float*)d_in[17];
  const float* lW       = (const float*)d_in[18];
  const float* lb       = (const float*)d_in[19];
  const float* lsW      = (const float*)d_in[20];
  const float* lsb      = (const float*)d_in[21];

  const int N = in_sizes[0] / H;
  const int E = in_sizes[1] / 2;
  const int* srcI = ei;
  const int* dstI = ei + E;

  float* out = (float*)d_out;
  float* GE = out;                              // [NG][EMB]
  float* NE = out + (size_t)NG*EMB;             // [N][EMB] f32
  float* XC = NE + (size_t)N*EMB;               // [NG][EMB]

  // ---- workspace layout ----
  unsigned short* xall = (unsigned short*)d_ws;             // [N][EMB] bf16 (post-BN2)
  unsigned short* h1   = xall + (size_t)N*EMB;              // [N][EMB] bf16
  unsigned short* h2   = h1 + (size_t)N*EMB;                // [N][EMB] bf16
  unsigned short* ub   = h1;                                // [N][H] (alias, conv loop)
  unsigned short* xpre = h2;                                // [N][EMB] pre-BN2 (alias: h2 used after pool)

  float* pooled  = (float*)(h2 + (size_t)N*EMB);            // [NG][EMB]
  float* gtmp1   = pooled + (size_t)NG*EMB;
  float* gtmp2   = gtmp1 + (size_t)NG*EMB;
  const int nrow = (N + 127)/128;                           // 391
  float* pa      = gtmp2 + (size_t)NG*EMB;                  // [nrow][256] BN1 partials
  float* pb      = pa + (size_t)nrow*256;                   // [nrow][256] BN2 partials
  float* bnsc2   = pb + (size_t)nrow*256;                   // [5][128]
  float* bnsf2   = bnsc2 + LNUM*128;                        // [5][128]
  float* biasNE  = bnsf2 + LNUM*128;                        // [640]
  unsigned short* W1t   = (unsigned short*)(biasNE + EMB);  // [L][H][H]
  unsigned short* W2t   = W1t + (size_t)LNUM*H*H;
  unsigned short* lWt01 = W2t + (size_t)LNUM*H*H;           // [2][EMB][EMB]
  unsigned short* Wcat  = lWt01 + (size_t)2*EMB*EMB;        // [EMB][2*EMB]
  int* rowptr = (int*)(Wcat + (size_t)2*EMB*EMB);           // [N+1]
  int* cursor = rowptr + (N + 1);                           // [N]
  int* colsrc = cursor + N;                                 // [E]
  int* gstart = colsrc + E;                                 // [NG+1]

  // CSR build (deterministic: segments sorted after scatter)
  k_zeroi<<<(N+255)/256, 256, 0, stream>>>(cursor, N);
  k_hist<<<(E+255)/256, 256, 0, stream>>>(dstI, E, cursor);
  k_scan<<<1, 1024, 0, stream>>>(cursor, rowptr, N);
  k_scatter<<<(E+255)/256, 256, 0, stream>>>(srcI, dstI, E, cursor, colsrc);
  k_sortseg<<<(N+255)/256, 256, 0, stream>>>(rowptr, colsrc, N);
  k_gstart<<<(NG+256)/256, 256, 0, stream>>>(batch, N, gstart);

  // weights -> bf16 transposed [n][k]
  const dim3 tb32(32, 8);
  k_castT<<<dim3(H/32, H/32, LNUM), tb32, 0, stream>>>(conv_W1, W1t, H, H, H, 0);
  k_castT<<<dim3(H/32, H/32, LNUM), tb32, 0, stream>>>(conv_W2, W2t, H, H, H, 0);
  k_castT<<<dim3(EMB/32, EMB/32, 2), tb32, 0, stream>>>(lW, lWt01, EMB, EMB, EMB, 0);
  k_castT<<<dim3(EMB/32, EMB/32, 1), tb32, 0, stream>>>(lW + (size_t)2*EMB*EMB, Wcat,
                                                        EMB, EMB, 2*EMB, 0);
  k_castT<<<dim3(EMB/32, EMB/32, 1), tb32, 0, stream>>>(lsW, Wcat, EMB, EMB, 2*EMB, EMB);
  k_bias2<<<1, EMB, 0, stream>>>(lb + (size_t)2*EMB, lsb, biasNE);

  const float invn = 1.0f / (float)N;

  for (int l = 0; l < LNUM; ++l){
    // ub = agg(h) @ W1 + b1  (fused gather; bf16 out; BN1 partials -> pa)
    if (l == 0)
      k_mmca<false><<<nrow, 512, 0, stream>>>(
          x, H, rowptr, colsrc, epsv, W1t, conv_b1, ub, H, pa, N);
    else
      k_mmca<true><<<nrow, 512, 0, stream>>>(
          xall + (size_t)(l-1)*H, EMB, rowptr, colsrc, epsv + l,
          W1t + (size_t)l*H*H, conv_b1 + l*H, ub, H, pa, N);

    // xpre[:,l*H:] = relu(bn1(ub)) @ W2 + b2  (BN1 from pa; BN2 partials -> pb)
    k_mmc2<<<nrow, 512, 0, stream>>>(
        ub, W2t + (size_t)l*H*H, conv_b2 + l*H,
        pa, conv_g1 + l*H, conv_be1 + l*H, invn,
        xpre + (size_t)l*H, EMB, pb, N);

    // BN2 finalize -> per-layer scale/shift (deterministic)
    k_bnfin2<<<1, 512, 0, stream>>>(pb, bn_g + l*H, bn_b + l*H,
                                    bnsc2 + l*128, bnsf2 + l*128, invn, nrow);

    // xall[:,l*H:] = bf16(relu(bn2(xpre)))
    k_bnapply<<<(N*32 + 255)/256, 256, 0, stream>>>(
        xpre + (size_t)l*H, EMB, bnsc2 + l*128, bnsf2 + l*128,
        xall + (size_t)l*H, EMB, N);
  }

  // pooling (BN2 applied in f32 from xpre) + prediction heads -> xcat
  k_pool<<<NG, 320, 0, stream>>>(xpre, bnsc2, bnsf2, gstart, pooled);
  k_pred<<<dim3(NG, LNUM), 128, 0, stream>>>(pooled, pred_W, pred_b, XC);

  // graph FF (f32, M=512): GE = relu-chain(XC) + XC @ gsW + gsb
  const dim3 gg((NG + 31)/32, EMB/64);          // (16, 10)
  k_gemm64<false,false><<<gg, 256, 0, stream>>>(XC, EMB, gsW, EMB, gsb,
                                                nullptr, 0, GE, EMB, NG, EMB, EMB);
  k_gemm64<true,false><<<gg, 256, 0, stream>>>(XC, EMB, gW, EMB, gb,
                                               nullptr, 0, gtmp1, EMB, NG, EMB, EMB);
  k_gemm64<true,false><<<gg, 256, 0, stream>>>(gtmp1, EMB, gW + (size_t)EMB*EMB, EMB, gb + EMB,
                                               nullptr, 0, gtmp2, EMB, NG, EMB, EMB);
  k_gemm64<true,true><<<gg, 256, 0, stream>>>(gtmp2, EMB, gW + (size_t)2*EMB*EMB, EMB, gb + 2*EMB,
                                              GE, EMB, GE, EMB, NG, EMB, EMB);

  // node FF (bf16 MFMA, 128x128 tile, depth-2 raw-barrier pipeline, XCD swizzle):
  const dim3 gn(EMB/128, nrow);                 // (5, 391)
  // h1 = relu(xall @ lW0 + lb0)
  k_mm<true,true,false><<<gn, 512, 0, stream>>>(
      xall, EMB, nullptr, lWt01, EMB, lb, h1, EMB, N, EMB);
  // h2 = relu(h1 @ lW1 + lb1)   (h2 aliases xpre — pool already consumed it)
  k_mm<true,true,false><<<gn, 512, 0, stream>>>(
      h1, EMB, nullptr, lWt01 + (size_t)EMB*EMB, EMB, lb + EMB, h2, EMB, N, EMB);
  // NE = [h2 | xall] @ [lW2 ; lsW] + (lb2 + lsb)   (dual-A, K=1280, f32 out)
  k_mm<false,false,true><<<gn, 512, 0, stream>>>(
      h2, EMB, xall, Wcat, 2*EMB, biasNE, NE, EMB, N, 2*EMB);
}

// Round 14
// 1227.345 us; speedup vs baseline: 1.2322x; 1.2322x over previous
//
#include <hip/hip_runtime.h>

constexpr int H    = 128;
constexpr int LNUM = 5;
constexpr int NG   = 512;
constexpr int EMB  = 640;   // LNUM * H
constexpr float BN_EPS = 1e-5f;

typedef __attribute__((ext_vector_type(8))) short bf16x8;
typedef __attribute__((ext_vector_type(4))) float f32x4;

__device__ inline unsigned short f2bf(float f){
  unsigned u = __builtin_bit_cast(unsigned, f);
  u += 0x7FFF + ((u >> 16) & 1);
  return (unsigned short)(u >> 16);
}
__device__ inline float bf2f(unsigned short h){
  unsigned u = ((unsigned)h) << 16;
  return __builtin_bit_cast(float, u);
}

// accumulate 8 bf16 (packed in uint4) into a[0..7]
__device__ inline void add8(float* a, uint4 v){
  a[0] += bf2f((unsigned short)v.x); a[1] += bf2f((unsigned short)(v.x >> 16));
  a[2] += bf2f((unsigned short)v.y); a[3] += bf2f((unsigned short)(v.y >> 16));
  a[4] += bf2f((unsigned short)v.z); a[5] += bf2f((unsigned short)(v.z >> 16));
  a[6] += bf2f((unsigned short)v.w); a[7] += bf2f((unsigned short)(v.w >> 16));
}

// bijective XCD chunk swizzle (m204)
__device__ inline int xcd_swz(int bid, int nwg){
  int q = nwg >> 3, r = nwg & 7;
  int xcd = bid & 7, idx = bid >> 3;
  return (xcd < r ? xcd*(q+1) : r*(q+1) + (xcd-r)*q) + idx;
}

// ---------------- utility ----------------
__global__ void k_zeroi(int* p, int n){
  int i = blockIdx.x*256 + threadIdx.x;
  if (i < n) p[i] = 0;
}

// ---------------- CSR build ----------------
__global__ void k_hist(const int* __restrict__ dst, int E, int* deg){
  int e = blockIdx.x*256 + threadIdx.x;
  if (e < E) atomicAdd(&deg[dst[e]], 1);
}

__global__ __launch_bounds__(1024) void k_scan(int* degcur, int* __restrict__ rowptr, int n){
  __shared__ int wsum[16];
  __shared__ int carry;
  int tid = threadIdx.x, wid = tid >> 6, lane = tid & 63;
  if (tid == 0){ carry = 0; rowptr[0] = 0; }
  __syncthreads();
  for (int base = 0; base < n; base += 1024){
    int v = (base + tid < n) ? degcur[base + tid] : 0;
    int s = v;
#pragma unroll
    for (int off = 1; off < 64; off <<= 1){
      int t = __shfl_up(s, off);
      if (lane >= off) s += t;
    }
    if (lane == 63) wsum[wid] = s;
    __syncthreads();
    if (wid == 0 && lane < 16){
      int wv = wsum[lane];
#pragma unroll
      for (int off = 1; off < 16; off <<= 1){
        int t = __shfl_up(wv, off);
        if (lane >= off) wv += t;
      }
      wsum[lane] = wv;
    }
    __syncthreads();
    int incl = s + (wid ? wsum[wid-1] : 0) + carry;
    if (base + tid < n){ rowptr[base + tid + 1] = incl; degcur[base + tid] = incl - v; }
    __syncthreads();
    if (tid == 0) carry += wsum[15];
    __syncthreads();
  }
}

__global__ void k_scatter(const int* __restrict__ src, const int* __restrict__ dst,
                          int E, int* cursor, int* __restrict__ colsrc){
  int e = blockIdx.x*256 + threadIdx.x;
  if (e < E){
    int d = dst[e];
    int pos = atomicAdd(&cursor[d], 1);
    colsrc[pos] = src[e];
  }
}

// deterministic neighbor order: sort each node's segment ascending
__global__ void k_sortseg(const int* __restrict__ rowptr, int* __restrict__ colsrc, int n){
  int node = blockIdx.x*256 + threadIdx.x;
  if (node < n){
    int lo = rowptr[node], hi = rowptr[node+1];
    for (int i = lo + 1; i < hi; ++i){
      int v = colsrc[i];
      int j = i - 1;
      while (j >= lo && colsrc[j] > v){ colsrc[j+1] = colsrc[j]; --j; }
      colsrc[j+1] = v;
    }
  }
}

__global__ void k_gstart(const int* __restrict__ batch, int N, int* __restrict__ gstart){
  int g = blockIdx.x*256 + threadIdx.x;
  if (g <= NG){
    int lo = 0, hi = N;
    while (lo < hi){
      int mid = (lo + hi) >> 1;
      if (batch[mid] < g) lo = mid + 1; else hi = mid;
    }
    gstart[g] = lo;
  }
}

// ---- weight cast+transpose: W[k][n] f32 -> Wt[n][ldt] bf16 at column offset koff ----
__global__ void k_castT(const float* __restrict__ W, unsigned short* __restrict__ Wt,
                        int K, int Nn, int ldt, int koff){
  __shared__ float sh[32][33];
  const size_t in_off  = (size_t)blockIdx.z * K * Nn;
  const size_t out_off = (size_t)blockIdx.z * Nn * ldt;
  int n0 = blockIdx.x*32, k0 = blockIdx.y*32;
  int tx = threadIdx.x, ty = threadIdx.y;   // 32 x 8
  for (int r = ty; r < 32; r += 8)
    sh[r][tx] = W[in_off + (size_t)(k0 + r)*Nn + n0 + tx];
  __syncthreads();
  for (int r = ty; r < 32; r += 8)
    Wt[out_off + (size_t)(n0 + r)*ldt + koff + k0 + tx] = f2bf(sh[tx][r]);
}

__global__ void k_bias2(const float* __restrict__ a, const float* __restrict__ b,
                        float* __restrict__ o){
  int i = threadIdx.x;
  o[i] = a[i] + b[i];
}

// ---------------- pooling (applies BN2+ReLU in f32 from pre-BN2 values) ----------------
__global__ __launch_bounds__(320) void k_pool(const unsigned short* __restrict__ xpre,
                                              const float* __restrict__ bnsc2,
                                              const float* __restrict__ bnsf2,
                                              const int* __restrict__ gstart,
                                              float* __restrict__ pooled){
  int g = blockIdx.x;
  int t = threadIdx.x;              // handles feats 2t, 2t+1
  int f0 = 2*t;
  int l = f0 >> 7, c = f0 & 127;
  float sc0 = bnsc2[l*128 + c],     sf0 = bnsf2[l*128 + c];
  float sc1 = bnsc2[l*128 + c + 1], sf1 = bnsf2[l*128 + c + 1];
  int n0 = gstart[g], n1 = gstart[g+1];
  float a0 = 0.f, a1 = 0.f;
  for (int n = n0; n < n1; ++n){
    unsigned u = ((const unsigned*)xpre)[(size_t)n*(EMB/2) + t];
    a0 += fmaxf(fmaf(sc0, bf2f((unsigned short)u),        sf0), 0.f);
    a1 += fmaxf(fmaf(sc1, bf2f((unsigned short)(u >> 16)), sf1), 0.f);
  }
  *(float2*)(pooled + (size_t)g*EMB + 2*t) = make_float2(a0, a1);
}

__global__ __launch_bounds__(128) void k_pred(const float* __restrict__ pooled,
                                              const float* __restrict__ W,
                                              const float* __restrict__ b,
                                              float* __restrict__ xcat){
  int g = blockIdx.x, l = blockIdx.y, o = threadIdx.x;
  __shared__ float sh[128];
  sh[o] = pooled[(size_t)g*EMB + l*H + o];
  __syncthreads();
  const float* Wl = W + (size_t)l*H*H;
  float acc = b[l*H + o];
  for (int k = 0; k < H; ++k) acc = fmaf(sh[k], Wl[k*H + o], acc);
  xcat[(size_t)g*EMB + l*H + o] = acc;
}

// ---- bf16 MFMA GEMM, 128x128 tile, BK=64, depth-2 pipeline, RAW s_barrier ----
template<bool RELU, bool OUT_BF16, bool DUAL>
__global__ __launch_bounds__(512) void k_mm(
    const unsigned short* __restrict__ A, int lda,
    const unsigned short* __restrict__ A2,
    const unsigned short* __restrict__ Bt, int ldb,
    const float* __restrict__ bias,
    void* __restrict__ Cv, int ldc,
    int M, int K)
{
  __shared__ union LdsU {
    unsigned short stage[2][2][8192];
    unsigned short sc16[128*136];
    float          sc32[128*132];
  } u;
  const int tid  = threadIdx.x;
  const int lane = tid & 63;
  const int w    = tid >> 6;
  const int wr   = w >> 2, wc = w & 3;

  const int nwg = gridDim.x * gridDim.y;
  const int bid = blockIdx.y * gridDim.x + blockIdx.x;
  const int wg  = xcd_swz(bid, nwg);
  const int col0 = (wg % gridDim.x) * 128;
  const int row0 = (wg / gridDim.x) * 128;
  const int KA   = DUAL ? (K >> 1) : K;

  const unsigned short *sA[2], *sA2p[2], *sB[2];
  int dOff[2];
#pragma unroll
  for (int j = 0; j < 2; ++j){
    int d = w*2048 + j*1024 + lane*16;
    int m = d >> 7;
    int inner = (d & 127) ^ ((m & 7) << 4);
    int gm = row0 + m; if (gm > M-1) gm = M-1;
    sA[j]  = A + (size_t)gm*lda + (inner >> 1);
    if (DUAL) sA2p[j] = A2 + (size_t)gm*lda + (inner >> 1);
    sB[j]  = Bt + (size_t)(col0 + m)*ldb + (inner >> 1);
    dOff[j] = w*2048 + j*1024;
  }

  f32x4 acc[4][2];
#pragma unroll
  for (int i = 0; i < 4; ++i)
#pragma unroll
    for (int j = 0; j < 2; ++j)
      acc[i][j] = (f32x4){0.f, 0.f, 0.f, 0.f};

  auto STAGE = [&](int buf, int kt){
    int k0 = kt*64, ka = k0;
    bool second = DUAL && (k0 >= KA);
    if (second) ka = k0 - KA;
#pragma unroll
    for (int j = 0; j < 2; ++j){
      const unsigned short* s = second ? (sA2p[j] + ka) : (sA[j] + ka);
      __builtin_amdgcn_global_load_lds(
          (const __attribute__((address_space(1))) void*)s,
          (__attribute__((address_space(3))) void*)((char*)&u.stage[buf][0][0] + dOff[j]),
          16, 0, 0);
    }
#pragma unroll
    for (int j = 0; j < 2; ++j)
      __builtin_amdgcn_global_load_lds(
          (const __attribute__((address_space(1))) void*)(sB[j] + k0),
          (__attribute__((address_space(3))) void*)((char*)&u.stage[buf][1][0] + dOff[j]),
          16, 0, 0);
  };

  const int NT = K / 64;
  STAGE(0, 0);
  STAGE(1, 1);
  asm volatile("s_waitcnt vmcnt(4)" ::: "memory");
  asm volatile("s_barrier" ::: "memory");

  for (int t = 0; t < NT; ++t){
    const char* Ab = (const char*)&u.stage[t & 1][0][0];
    const char* Bb = (const char*)&u.stage[t & 1][1][0];
    bf16x8 af[2][4], bq[2][2];
#pragma unroll
    for (int kk = 0; kk < 2; ++kk){
      const int kb = kk*64 + ((lane >> 4) << 4);
#pragma unroll
      for (int i = 0; i < 4; ++i){
        int row = wr*64 + i*16 + (lane & 15);
        af[kk][i] = *(const bf16x8*)(Ab + ((row*128 + kb) ^ ((row & 7) << 4)));
      }
#pragma unroll
      for (int j = 0; j < 2; ++j){
        int col = wc*32 + j*16 + (lane & 15);
        bq[kk][j] = *(const bf16x8*)(Bb + ((col*128 + kb) ^ ((col & 7) << 4)));
      }
    }
    if (t + 2 < NT){
      asm volatile("s_barrier" ::: "memory");
      STAGE(t & 1, t + 2);
    }
#pragma unroll
    for (int kk = 0; kk < 2; ++kk)
#pragma unroll
      for (int i = 0; i < 4; ++i)
#pragma unroll
        for (int j = 0; j < 2; ++j)
          acc[i][j] = __builtin_amdgcn_mfma_f32_16x16x32_bf16(af[kk][i], bq[kk][j], acc[i][j], 0, 0, 0);
    if (t + 1 < NT){
      if (t + 2 < NT) asm volatile("s_waitcnt vmcnt(4)" ::: "memory");
      else            asm volatile("s_waitcnt vmcnt(0)" ::: "memory");
      asm volatile("s_barrier" ::: "memory");
    }
  }

  __syncthreads();
  if (OUT_BF16){
#pragma unroll
    for (int j = 0; j < 2; ++j){
      int cl = wc*32 + j*16 + (lane & 15);
      float bs = bias[col0 + cl];
#pragma unroll
      for (int i = 0; i < 4; ++i){
        int rb = wr*64 + i*16 + ((lane >> 4) << 2);
#pragma unroll
        for (int r = 0; r < 4; ++r){
          float v = acc[i][j][r] + bs;
          if (RELU) v = fmaxf(v, 0.f);
          u.sc16[(rb + r)*136 + cl] = f2bf(v);
        }
      }
    }
    __syncthreads();
    unsigned short* Cb = (unsigned short*)Cv;
    for (int idx = tid; idx < 128*16; idx += 512){
      int rr = idx >> 4, seg = idx & 15;
      int grow = row0 + rr;
      if (grow < M){
        uint4 vv = *(const uint4*)&u.sc16[rr*136 + seg*8];
        *(uint4*)(Cb + (size_t)grow*ldc + col0 + seg*8) = vv;
      }
    }
  } else {
#pragma unroll
    for (int j = 0; j < 2; ++j){
      int cl = wc*32 + j*16 + (lane & 15);
      float bs = bias[col0 + cl];
#pragma unroll
      for (int i = 0; i < 4; ++i){
        int rb = wr*64 + i*16 + ((lane >> 4) << 2);
#pragma unroll
        for (int r = 0; r < 4; ++r){
          float v = acc[i][j][r] + bs;
          if (RELU) v = fmaxf(v, 0.f);
          u.sc32[(rb + r)*132 + cl] = v;
        }
      }
    }
    __syncthreads();
    float* Cf = (float*)Cv;
    for (int idx = tid; idx < 128*32; idx += 512){
      int rr = idx >> 5, seg = idx & 31;
      int grow = row0 + rr;
      if (grow < M){
        float4 vv = *(const float4*)&u.sc32[rr*132 + seg*4];
        *(float4*)(Cf + (size_t)grow*ldc + col0 + seg*4) = vv;
      }
    }
  }
}

// ------- fused GIN-aggregate + conv GEMM1 + deterministic block stats -------
// Gather: 4 threads/node (round-11 form), batched uint4 loads, x2 edge unroll.
// Deterministic: colsrc segments are pre-sorted; f32 adds in fixed order.
template<bool IN_BF16>
__global__ __launch_bounds__(512) void k_mmca(
    const void* __restrict__ hin, int ldh,
    const int* __restrict__ rowptr, const int* __restrict__ colsrc,
    const float* __restrict__ epsp,
    const unsigned short* __restrict__ Bt,
    const float* __restrict__ bias,
    unsigned short* __restrict__ C, int ldc,
    float* __restrict__ pa,
    int M)
{
  __shared__ unsigned short shm[2*128*128];
  __shared__ float sbs[2][128], sbq[2][128];
  unsigned short* As = shm;
  unsigned short* Bs = shm + 16384;
  const int tid  = threadIdx.x;
  const int lane = tid & 63;
  const int w    = tid >> 6;
  const int wr   = w >> 2, wc = w & 3;

  const int wg   = xcd_swz(blockIdx.x, gridDim.x);
  const int row0 = wg * 128;

  // issue B staging first (pre-swizzled source, linear dest)
#pragma unroll
  for (int j = 0; j < 4; ++j){
    int d = w*4096 + j*1024 + lane*16;
    int m = d >> 8;
    int inner = (d & 255) ^ ((m & 15) << 4);
    __builtin_amdgcn_global_load_lds(
        (const __attribute__((address_space(1))) void*)(Bt + (size_t)m*H + (inner >> 1)),
        (__attribute__((address_space(3))) void*)((char*)Bs + w*4096 + j*1024),
        16, 0, 0);
  }

  // gather A: thread handles row r = tid>>2, 32 cols at c0 = (tid&3)*32
  {
    int r  = tid >> 2;
    int c0 = (tid & 3) << 5;
    int node = row0 + r; if (node > M-1) node = M-1;
    float ep = 1.0f + *epsp;
    float a[32];
    if (IN_BF16){
      const unsigned short* src = (const unsigned short*)hin + (size_t)node*ldh + c0;
      uint4 v0 = *(const uint4*)(src);
      uint4 v1 = *(const uint4*)(src + 8);
      uint4 v2 = *(const uint4*)(src + 16);
      uint4 v3 = *(const uint4*)(src + 24);
#pragma unroll
      for (int q = 0; q < 32; ++q) a[q] = 0.f;
      add8(a,      v0); add8(a + 8,  v1); add8(a + 16, v2); add8(a + 24, v3);
#pragma unroll
      for (int q = 0; q < 32; ++q) a[q] *= ep;
    } else {
      const float* src = (const float*)hin + (size_t)node*ldh + c0;
#pragma unroll
      for (int q = 0; q < 32; q += 4){
        float4 f = *(const float4*)(src + q);
        a[q] = ep*f.x; a[q+1] = ep*f.y; a[q+2] = ep*f.z; a[q+3] = ep*f.w;
      }
    }
    int e = rowptr[node], e1 = rowptr[node+1];
    if (IN_BF16){
      for (; e + 2 <= e1; e += 2){            // 2 edges in flight (8 x 16B loads)
        int s0 = colsrc[e], s1 = colsrc[e+1];
        const unsigned short* p0 = (const unsigned short*)hin + (size_t)s0*ldh + c0;
        const unsigned short* p1 = (const unsigned short*)hin + (size_t)s1*ldh + c0;
        uint4 w0 = *(const uint4*)(p0);
        uint4 w1 = *(const uint4*)(p0 + 8);
        uint4 w2 = *(const uint4*)(p0 + 16);
        uint4 w3 = *(const uint4*)(p0 + 24);
        uint4 y0 = *(const uint4*)(p1);
        uint4 y1 = *(const uint4*)(p1 + 8);
        uint4 y2 = *(const uint4*)(p1 + 16);
        uint4 y3 = *(const uint4*)(p1 + 24);
        add8(a,      w0); add8(a + 8,  w1); add8(a + 16, w2); add8(a + 24, w3);
        add8(a,      y0); add8(a + 8,  y1); add8(a + 16, y2); add8(a + 24, y3);
      }
      for (; e < e1; ++e){
        int s = colsrc[e];
        const unsigned short* p = (const unsigned short*)hin + (size_t)s*ldh + c0;
        uint4 w0 = *(const uint4*)(p);
        uint4 w1 = *(const uint4*)(p + 8);
        uint4 w2 = *(const uint4*)(p + 16);
        uint4 w3 = *(const uint4*)(p + 24);
        add8(a,      w0); add8(a + 8,  w1); add8(a + 16, w2); add8(a + 24, w3);
      }
    } else {
      for (; e < e1; ++e){
        int s = colsrc[e];
        const float* p = (const float*)hin + (size_t)s*ldh + c0;
#pragma unroll
        for (int q = 0; q < 32; q += 4){
          float4 f = *(const float4*)(p + q);
          a[q] += f.x; a[q+1] += f.y; a[q+2] += f.z; a[q+3] += f.w;
        }
      }
    }
    // write 32 bf16 (64 B = 4 swizzled 16-B chunks) into As
#pragma unroll
    for (int q = 0; q < 4; ++q){
      unsigned pk[4];
#pragma unroll
      for (int k = 0; k < 4; ++k)
        pk[k] = (unsigned)f2bf(a[q*8 + 2*k]) | ((unsigned)f2bf(a[q*8 + 2*k + 1]) << 16);
      int byte = (r*256 + (tid & 3)*64 + q*16) ^ ((r & 15) << 4);
      *(uint4*)((char*)As + byte) = *(uint4*)pk;
    }
  }

  asm volatile("s_waitcnt vmcnt(0)" ::: "memory");
  __syncthreads();

  f32x4 acc[4][2];
#pragma unroll
  for (int i = 0; i < 4; ++i)
#pragma unroll
    for (int j = 0; j < 2; ++j)
      acc[i][j] = (f32x4){0.f, 0.f, 0.f, 0.f};

#pragma unroll
  for (int kk = 0; kk < 4; ++kk){
    const int kb = kk*64 + ((lane >> 4) << 4);
    bf16x8 af[4], bfr[2];
#pragma unroll
    for (int i = 0; i < 4; ++i){
      int row = wr*64 + i*16 + (lane & 15);
      af[i] = *(const bf16x8*)((const char*)As + ((row*256 + kb) ^ ((row & 15) << 4)));
    }
#pragma unroll
    for (int j = 0; j < 2; ++j){
      int col = wc*32 + j*16 + (lane & 15);
      bfr[j] = *(const bf16x8*)((const char*)Bs + ((col*256 + kb) ^ ((col & 15) << 4)));
    }
#pragma unroll
    for (int i = 0; i < 4; ++i)
#pragma unroll
      for (int j = 0; j < 2; ++j)
        acc[i][j] = __builtin_amdgcn_mfma_f32_16x16x32_bf16(af[i], bfr[j], acc[i][j], 0, 0, 0);
  }

  // deterministic block stats: wave partials -> LDS -> single combine -> pa
#pragma unroll
  for (int j = 0; j < 2; ++j){
    int col = wc*32 + j*16 + (lane & 15);
    float bs = bias[col];
    float s = 0.f, q = 0.f;
#pragma unroll
    for (int i = 0; i < 4; ++i){
      int rb = row0 + wr*64 + i*16 + ((lane >> 4) << 2);
#pragma unroll
      for (int r = 0; r < 4; ++r){
        if (rb + r < M){
          float v = acc[i][j][r] + bs;
          s += v; q += v*v;
        }
      }
    }
    s += __shfl_xor(s, 16); q += __shfl_xor(q, 16);
    s += __shfl_xor(s, 32); q += __shfl_xor(q, 32);
    if (lane < 16){ sbs[wr][col] = s; sbq[wr][col] = q; }
  }
  __syncthreads();
  if (tid < 128){
    pa[(size_t)wg*256 + tid]       = sbs[0][tid] + sbs[1][tid];
    pa[(size_t)wg*256 + 128 + tid] = sbq[0][tid] + sbq[1][tid];
  }

  // epilogue: transpose via LDS (staging dead), coalesced 16-B stores
  __syncthreads();
#pragma unroll
  for (int j = 0; j < 2; ++j){
    int cl = wc*32 + j*16 + (lane & 15);
    float bs = bias[cl];
#pragma unroll
    for (int i = 0; i < 4; ++i){
      int rb = wr*64 + i*16 + ((lane >> 4) << 2);
#pragma unroll
      for (int r = 0; r < 4; ++r)
        shm[(rb + r)*136 + cl] = f2bf(acc[i][j][r] + bs);
    }
  }
  __syncthreads();
  for (int idx = tid; idx < 128*16; idx += 512){
    int rr = idx >> 4, seg = idx & 15;
    int grow = row0 + rr;
    if (grow < M){
      uint4 vv = *(const uint4*)&shm[rr*136 + seg*8];
      *(uint4*)(C + (size_t)grow*ldc + seg*8) = vv;
    }
  }
}

// ------- conv GEMM2: BN1 scale/shift from global (precomputed) + block stats to pb -------
__global__ __launch_bounds__(512) void k_mmc2(
    const unsigned short* __restrict__ A,     // [M][128] bf16 (pre-BN1)
    const unsigned short* __restrict__ Bt,
    const float* __restrict__ bias,
    const float* __restrict__ sc1, const float* __restrict__ sf1,  // BN1 scale/shift
    unsigned short* __restrict__ C, int ldc,
    float* __restrict__ pb,                   // [nwg][256] BN2 partials
    int M)
{
  __shared__ unsigned short shm[2*128*128];
  __shared__ float bnsc[128], bnsf[128];
  __shared__ float rs[2][128], rq[2][128];
  unsigned short* As = shm;
  unsigned short* Bs = shm + 16384;
  const int tid  = threadIdx.x;
  const int lane = tid & 63;
  const int w    = tid >> 6;
  const int wr   = w >> 2, wc = w & 3;
  const int nwg  = gridDim.x;

  const int wg   = xcd_swz(blockIdx.x, nwg);
  const int row0 = wg * 128;

#pragma unroll
  for (int j = 0; j < 4; ++j){
    int d = w*4096 + j*1024 + lane*16;
    int m = d >> 8;
    int inner = (d & 255) ^ ((m & 15) << 4);
    int gm = row0 + m; if (gm > M-1) gm = M-1;
    __builtin_amdgcn_global_load_lds(
        (const __attribute__((address_space(1))) void*)(A + (size_t)gm*H + (inner >> 1)),
        (__attribute__((address_space(3))) void*)((char*)As + w*4096 + j*1024),
        16, 0, 0);
    __builtin_amdgcn_global_load_lds(
        (const __attribute__((address_space(1))) void*)(Bt + (size_t)m*H + (inner >> 1)),
        (__attribute__((address_space(3))) void*)((char*)Bs + w*4096 + j*1024),
        16, 0, 0);
  }

  // BN1 scale/shift: plain load (overlaps with staging)
  if (tid < 128){
    bnsc[tid] = sc1[tid];
    bnsf[tid] = sf1[tid];
  }

  asm volatile("s_waitcnt vmcnt(0)" ::: "memory");
  __syncthreads();

  f32x4 acc[4][2];
#pragma unroll
  for (int i = 0; i < 4; ++i)
#pragma unroll
    for (int j = 0; j < 2; ++j)
      acc[i][j] = (f32x4){0.f, 0.f, 0.f, 0.f};

#pragma unroll
  for (int kk = 0; kk < 4; ++kk){
    const int kb = kk*64 + ((lane >> 4) << 4);
    bf16x8 af[4], bfr[2];
#pragma unroll
    for (int i = 0; i < 4; ++i){
      int row = wr*64 + i*16 + (lane & 15);
      af[i] = *(const bf16x8*)((const char*)As + ((row*256 + kb) ^ ((row & 15) << 4)));
    }
#pragma unroll
    for (int j = 0; j < 2; ++j){
      int col = wc*32 + j*16 + (lane & 15);
      bfr[j] = *(const bf16x8*)((const char*)Bs + ((col*256 + kb) ^ ((col & 15) << 4)));
    }
    {
      int k8 = kk*32 + ((lane >> 4) << 3);
      float4 s0 = *(const float4*)(&bnsc[k8]), s1 = *(const float4*)(&bnsc[k8 + 4]);
      float4 f0 = *(const float4*)(&bnsf[k8]), f1 = *(const float4*)(&bnsf[k8 + 4]);
      float sc[8] = {s0.x,s0.y,s0.z,s0.w,s1.x,s1.y,s1.z,s1.w};
      float sf[8] = {f0.x,f0.y,f0.z,f0.w,f1.x,f1.y,f1.z,f1.w};
#pragma unroll
      for (int i = 0; i < 4; ++i){
        bf16x8 aa = af[i], o;
#pragma unroll
        for (int jj = 0; jj < 8; ++jj){
          float v = fmaxf(fmaf(sc[jj], bf2f((unsigned short)aa[jj]), sf[jj]), 0.f);
          o[jj] = (short)f2bf(v);
        }
        af[i] = o;
      }
    }
#pragma unroll
    for (int i = 0; i < 4; ++i)
#pragma unroll
      for (int j = 0; j < 2; ++j)
        acc[i][j] = __builtin_amdgcn_mfma_f32_16x16x32_bf16(af[i], bfr[j], acc[i][j], 0, 0, 0);
  }

  // deterministic block stats -> pb
#pragma unroll
  for (int j = 0; j < 2; ++j){
    int col = wc*32 + j*16 + (lane & 15);
    float bs = bias[col];
    float s = 0.f, q = 0.f;
#pragma unroll
    for (int i = 0; i < 4; ++i){
      int rb = row0 + wr*64 + i*16 + ((lane >> 4) << 2);
#pragma unroll
      for (int r = 0; r < 4; ++r){
        if (rb + r < M){
          float v = acc[i][j][r] + bs;
          s += v; q += v*v;
        }
      }
    }
    s += __shfl_xor(s, 16); q += __shfl_xor(q, 16);
    s += __shfl_xor(s, 32); q += __shfl_xor(q, 32);
    if (lane < 16){ rs[wr][col] = s; rq[wr][col] = q; }
  }
  __syncthreads();
  if (tid < 128){
    pb[(size_t)wg*256 + tid]       = rs[0][tid] + rs[1][tid];
    pb[(size_t)wg*256 + 128 + tid] = rq[0][tid] + rq[1][tid];
  }

  __syncthreads();
#pragma unroll
  for (int j = 0; j < 2; ++j){
    int cl = wc*32 + j*16 + (lane & 15);
    float bs = bias[cl];
#pragma unroll
    for (int i = 0; i < 4; ++i){
      int rb = wr*64 + i*16 + ((lane >> 4) << 2);
#pragma unroll
      for (int r = 0; r < 4; ++r)
        shm[(rb + r)*136 + cl] = f2bf(acc[i][j][r] + bs);
    }
  }
  __syncthreads();
  for (int idx = tid; idx < 128*16; idx += 512){
    int rr = idx >> 4, seg = idx & 15;
    int grow = row0 + rr;
    if (grow < M){
      uint4 vv = *(const uint4*)&shm[rr*136 + seg*8];
      *(uint4*)(C + (size_t)grow*ldc + seg*8) = vv;
    }
  }
}

// ---- BN finalize: deterministic reduction of partials -> scale/shift ----
__global__ __launch_bounds__(512) void k_bnfin2(const float* __restrict__ pp,
                                                const float* __restrict__ g,
                                                const float* __restrict__ b,
                                                float* __restrict__ scale,
                                                float* __restrict__ shift,
                                                float invn, int nwg){
  __shared__ float rs[4][128], rq[4][128];
  int tid = threadIdx.x;
  int c = tid & 127, part = tid >> 7;
  float s = 0.f, q = 0.f;
  for (int bi = part; bi < nwg; bi += 4){
    s += pp[(size_t)bi*256 + c];
    q += pp[(size_t)bi*256 + 128 + c];
  }
  rs[part][c] = s; rq[part][c] = q;
  __syncthreads();
  if (tid < 128){
    float S = rs[0][tid] + rs[1][tid] + rs[2][tid] + rs[3][tid];
    float Q = rq[0][tid] + rq[1][tid] + rq[2][tid] + rq[3][tid];
    float m = S*invn;
    float v = Q*invn - m*m;
    float inv = rsqrtf(v + BN_EPS);
    float sc = g[tid]*inv;
    scale[tid] = sc;
    shift[tid] = b[tid] - m*sc;
  }
}

// ---- BN2 apply: out = bf16(relu(sc*U+sf)), U stride ldu ----
__global__ __launch_bounds__(256) void k_bnapply(const unsigned short* __restrict__ U,
                                                 int ldu,
                                                 const float* __restrict__ scale,
                                                 const float* __restrict__ shift,
                                                 unsigned short* __restrict__ out,
                                                 int ldo, int n){
  int i = blockIdx.x*256 + threadIdx.x;
  int total = n * (H/4);
  if (i < total){
    int r = i >> 5;
    int c4 = (i & 31) << 2;
    uint2 up = *(const uint2*)(U + (size_t)r*ldu + c4);
    float4 sc = *(const float4*)(scale + c4);
    float4 sf = *(const float4*)(shift + c4);
    float a = fmaxf(fmaf(sc.x, bf2f((unsigned short)up.x),       sf.x), 0.f);
    float c = fmaxf(fmaf(sc.y, bf2f((unsigned short)(up.x>>16)), sf.y), 0.f);
    float d = fmaxf(fmaf(sc.z, bf2f((unsigned short)up.y),       sf.z), 0.f);
    float e = fmaxf(fmaf(sc.w, bf2f((unsigned short)(up.y>>16)), sf.w), 0.f);
    uint2 o;
    o.x = (unsigned)f2bf(a) | ((unsigned)f2bf(c) << 16);
    o.y = (unsigned)f2bf(d) | ((unsigned)f2bf(e) << 16);
    *(uint2*)(out + (size_t)r*ldo + c4) = o;
  }
}

// ---------------- f32 GEMM 32x64 tile (graph FF, M=512) ----------------
template<bool RELU, bool ADD_D>
__global__ __launch_bounds__(256) void k_gemm64(
    const float* __restrict__ A, int lda,
    const float* __restrict__ B, int ldb,
    const float* __restrict__ bias,
    const float* D, int ldd,
    float* C, int ldc,
    int M, int N, int K)
{
  __shared__ float As[32][36];
  __shared__ float Bs[32][64];
  const int tid  = threadIdx.x;
  const int tx   = tid & 15;
  const int ty   = tid >> 4;
  const int row0 = blockIdx.x * 32;
  const int col0 = blockIdx.y * 64;
  const int am = tid >> 3;
  const int ak = (tid & 7) << 2;
  const int bk = tid >> 4;
  const int bn = (tid & 15) << 2;
  float acc[2][4] = {};

  for (int k0 = 0; k0 < K; k0 += 32){
    {
      int gr = row0 + am;
      float4 v = make_float4(0.f, 0.f, 0.f, 0.f);
      if (gr < M) v = *(const float4*)(A + (size_t)gr*lda + k0 + ak);
      As[ak+0][am]=v.x; As[ak+1][am]=v.y; As[ak+2][am]=v.z; As[ak+3][am]=v.w;
    }
#pragma unroll
    for (int h = 0; h < 2; ++h){
      int kk = bk + h*16;
      *(float4*)(&Bs[kk][bn]) = *(const float4*)(B + (size_t)(k0+kk)*ldb + col0 + bn);
    }
    __syncthreads();
#pragma unroll 8
    for (int k = 0; k < 32; ++k){
      float2 a = *(const float2*)(&As[k][ty<<1]);
      float4 b = *(const float4*)(&Bs[k][tx<<2]);
      float av[2] = {a.x, a.y};
      float bv[4] = {b.x, b.y, b.z, b.w};
#pragma unroll
      for (int i = 0; i < 2; ++i)
#pragma unroll
        for (int j = 0; j < 4; ++j)
          acc[i][j] = fmaf(av[i], bv[j], acc[i][j]);
    }
    __syncthreads();
  }

  const int col = col0 + (tx<<2);
  float4 bv = *(const float4*)(bias + col);
#pragma unroll
  for (int i = 0; i < 2; ++i){
    int row = row0 + (ty<<1) + i;
    if (row < M){
      float r[4] = {acc[i][0]+bv.x, acc[i][1]+bv.y, acc[i][2]+bv.z, acc[i][3]+bv.w};
      if (RELU){
#pragma unroll
        for (int j = 0; j < 4; ++j) r[j] = fmaxf(r[j], 0.f);
      }
      if (ADD_D){
        float4 d = *(const float4*)(D + (size_t)row*ldd + col);
        r[0]+=d.x; r[1]+=d.y; r[2]+=d.z; r[3]+=d.w;
      }
      *(float4*)(C + (size_t)row*ldc + col) = make_float4(r[0],r[1],r[2],r[3]);
    }
  }
}

// ---------------- host ----------------
extern "C" void kernel_launch(void* const* d_in, const int* in_sizes, int n_in,
                              void* d_out, int out_size, void* d_ws, size_t ws_size,
                              hipStream_t stream) {
  const float* x        = (const float*)d_in[0];
  const int*   ei       = (const int*)d_in[1];
  const int*   batch    = (const int*)d_in[2];
  const float* conv_W1  = (const float*)d_in[3];
  const float* conv_b1  = (const float*)d_in[4];
  const float* conv_g1  = (const float*)d_in[5];
  const float* conv_be1 = (const float*)d_in[6];
  const float* conv_W2  = (const float*)d_in[7];
  const float* conv_b2  = (const float*)d_in[8];
  const float* epsv     = (const float*)d_in[9];
  const float* bn_g     = (const float*)d_in[10];
  const float* bn_b     = (const float*)d_in[11];
  const float* pred_W   = (const float*)d_in[12];
  const float* pred_b   = (const float*)d_in[13];
  const float* gW       = (const float*)d_in[14];
  const float* gb       = (const float*)d_in[15];
  const float* gsW      = (const float*)d_in[16];
  const float* gsb      = (const float*)d_in[17];
  const float* lW       = (const float*)d_in[18];
  const float* lb       = (const float*)d_in[19];
  const float* lsW      = (const float*)d_in[20];
  const float* lsb      = (const float*)d_in[21];

  const int N = in_sizes[0] / H;
  const int E = in_sizes[1] / 2;
  const int* srcI = ei;
  const int* dstI = ei + E;

  float* out = (float*)d_out;
  float* GE = out;                              // [NG][EMB]
  float* NE = out + (size_t)NG*EMB;             // [N][EMB] f32
  float* XC = NE + (size_t)N*EMB;               // [NG][EMB]

  // ---- workspace layout ----
  unsigned short* xall = (unsigned short*)d_ws;             // [N][EMB] bf16 (post-BN2)
  unsigned short* h1   = xall + (size_t)N*EMB;              // [N][EMB] bf16
  unsigned short* h2   = h1 + (size_t)N*EMB;                // [N][EMB] bf16
  unsigned short* ub   = h1;                                // [N][H] (alias, conv loop)
  unsigned short* xpre = h2;                                // [N][EMB] pre-BN2 (h2 reused after pool)

  float* pooled  = (float*)(h2 + (size_t)N*EMB);            // [NG][EMB]
  float* gtmp1   = pooled + (size_t)NG*EMB;
  float* gtmp2   = gtmp1 + (size_t)NG*EMB;
  const int nrow = (N + 127)/128;                           // 391
  float* pa      = gtmp2 + (size_t)NG*EMB;                  // [nrow][256] BN1 partials
  float* pb      = pa + (size_t)nrow*256;                   // [nrow][256] BN2 partials
  float* bnsc2   = pb + (size_t)nrow*256;                   // [5][128]
  float* bnsf2   = bnsc2 + LNUM*128;                        // [5][128]
  float* bnsc1   = bnsf2 + LNUM*128;                        // [128]
  float* bnsf1   = bnsc1 + 128;                             // [128]
  float* biasNE  = bnsf1 + 128;                             // [640]
  unsigned short* W1t   = (unsigned short*)(biasNE + EMB);  // [L][H][H]
  unsigned short* W2t   = W1t + (size_t)LNUM*H*H;
  unsigned short* lWt01 = W2t + (size_t)LNUM*H*H;           // [2][EMB][EMB]
  unsigned short* Wcat  = lWt01 + (size_t)2*EMB*EMB;        // [EMB][2*EMB]
  int* rowptr = (int*)(Wcat + (size_t)2*EMB*EMB);           // [N+1]
  int* cursor = rowptr + (N + 1);                           // [N]
  int* colsrc = cursor + N;                                 // [E]
  int* gstart = colsrc + E;                                 // [NG+1]

  // CSR build (deterministic: segments sorted after scatter)
  k_zeroi<<<(N+255)/256, 256, 0, stream>>>(cursor, N);
  k_hist<<<(E+255)/256, 256, 0, stream>>>(dstI, E, cursor);
  k_scan<<<1, 1024, 0, stream>>>(cursor, rowptr, N);
  k_scatter<<<(E+255)/256, 256, 0, stream>>>(srcI, dstI, E, cursor, colsrc);
  k_sortseg<<<(N+255)/256, 256, 0, stream>>>(rowptr, colsrc, N);
  k_gstart<<<(NG+256)/256, 256, 0, stream>>>(batch, N, gstart);

  // weights -> bf16 transposed [n][k]
  const dim3 tb32(32, 8);
  k_castT<<<dim3(H/32, H/32, LNUM), tb32, 0, stream>>>(conv_W1, W1t, H, H, H, 0);
  k_castT<<<dim3(H/32, H/32, LNUM), tb32, 0, stream>>>(conv_W2, W2t, H, H, H, 0);
  k_castT<<<dim3(EMB/32, EMB/32, 2), tb32, 0, stream>>>(lW, lWt01, EMB, EMB, EMB, 0);
  k_castT<<<dim3(EMB/32, EMB/32, 1), tb32, 0, stream>>>(lW + (size_t)2*EMB*EMB, Wcat,
                                                        EMB, EMB, 2*EMB, 0);
  k_castT<<<dim3(EMB/32, EMB/32, 1), tb32, 0, stream>>>(lsW, Wcat, EMB, EMB, 2*EMB, EMB);
  k_bias2<<<1, EMB, 0, stream>>>(lb + (size_t)2*EMB, lsb, biasNE);

  const float invn = 1.0f / (float)N;

  for (int l = 0; l < LNUM; ++l){
    // ub = agg(h) @ W1 + b1  (fused gather; bf16 out; BN1 partials -> pa)
    if (l == 0)
      k_mmca<false><<<nrow, 512, 0, stream>>>(
          x, H, rowptr, colsrc, epsv, W1t, conv_b1, ub, H, pa, N);
    else
      k_mmca<true><<<nrow, 512, 0, stream>>>(
          xall + (size_t)(l-1)*H, EMB, rowptr, colsrc, epsv + l,
          W1t + (size_t)l*H*H, conv_b1 + l*H, ub, H, pa, N);

    // BN1 finalize (once, deterministic)
    k_bnfin2<<<1, 512, 0, stream>>>(pa, conv_g1 + l*H, conv_be1 + l*H,
                                    bnsc1, bnsf1, invn, nrow);

    // xpre[:,l*H:] = relu(bn1(ub)) @ W2 + b2  (BN2 partials -> pb)
    k_mmc2<<<nrow, 512, 0, stream>>>(
        ub, W2t + (size_t)l*H*H, conv_b2 + l*H,
        bnsc1, bnsf1,
        xpre + (size_t)l*H, EMB, pb, N);

    // BN2 finalize -> per-layer scale/shift (deterministic)
    k_bnfin2<<<1, 512, 0, stream>>>(pb, bn_g + l*H, bn_b + l*H,
                                    bnsc2 + l*128, bnsf2 + l*128, invn, nrow);

    // xall[:,l*H:] = bf16(relu(bn2(xpre)))
    k_bnapply<<<(N*32 + 255)/256, 256, 0, stream>>>(
        xpre + (size_t)l*H, EMB, bnsc2 + l*128, bnsf2 + l*128,
        xall + (size_t)l*H, EMB, N);
  }

  // pooling (BN2 applied in f32 from xpre) + prediction heads -> xcat
  k_pool<<<NG, 320, 0, stream>>>(xpre, bnsc2, bnsf2, gstart, pooled);
  k_pred<<<dim3(NG, LNUM), 128, 0, stream>>>(pooled, pred_W, pred_b, XC);

  // graph FF (f32, M=512): GE = relu-chain(XC) + XC @ gsW + gsb
  const dim3 gg((NG + 31)/32, EMB/64);          // (16, 10)
  k_gemm64<false,false><<<gg, 256, 0, stream>>>(XC, EMB, gsW, EMB, gsb,
                                                nullptr, 0, GE, EMB, NG, EMB, EMB);
  k_gemm64<true,false><<<gg, 256, 0, stream>>>(XC, EMB, gW, EMB, gb,
                                               nullptr, 0, gtmp1, EMB, NG, EMB, EMB);
  k_gemm64<true,false><<<gg, 256, 0, stream>>>(gtmp1, EMB, gW + (size_t)EMB*EMB, EMB, gb + EMB,
                                               nullptr, 0, gtmp2, EMB, NG, EMB, EMB);
  k_gemm64<true,true><<<gg, 256, 0, stream>>>(gtmp2, EMB, gW + (size_t)2*EMB*EMB, EMB, gb + 2*EMB,
                                              GE, EMB, GE, EMB, NG, EMB, EMB);

  // node FF (bf16 MFMA, 128x128 tile, depth-2 raw-barrier pipeline, XCD swizzle):
  const dim3 gn(EMB/128, nrow);                 // (5, 391)
  // h1 = relu(xall @ lW0 + lb0)
  k_mm<true,true,false><<<gn, 512, 0, stream>>>(
      xall, EMB, nullptr, lWt01, EMB, lb, h1, EMB, N, EMB);
  // h2 = relu(h1 @ lW1 + lb1)   (h2 aliases xpre — pool already consumed it)
  k_mm<true,true,false><<<gn, 512, 0, stream>>>(
      h1, EMB, nullptr, lWt01 + (size_t)EMB*EMB, EMB, lb + EMB, h2, EMB, N, EMB);
  // NE = [h2 | xall] @ [lW2 ; lsW] + (lb2 + lsb)   (dual-A, K=1280, f32 out)
  k_mm<false,false,true><<<gn, 512, 0, stream>>>(
      h2, EMB, xall, Wcat, 2*EMB, biasNE, NE, EMB, N, 2*EMB);
}

// Round 15
// 1018.692 us; speedup vs baseline: 1.4846x; 1.2048x over previous
//
#include <hip/hip_runtime.h>

constexpr int H    = 128;
constexpr int LNUM = 5;
constexpr int NG   = 512;
constexpr int EMB  = 640;   // LNUM * H
constexpr float BN_EPS = 1e-5f;

typedef __attribute__((ext_vector_type(8))) short bf16x8;
typedef __attribute__((ext_vector_type(4))) float f32x4;

__device__ inline unsigned short f2bf(float f){
  unsigned u = __builtin_bit_cast(unsigned, f);
  u += 0x7FFF + ((u >> 16) & 1);
  return (unsigned short)(u >> 16);
}
__device__ inline float bf2f(unsigned short h){
  unsigned u = ((unsigned)h) << 16;
  return __builtin_bit_cast(float, u);
}

// accumulate 8 bf16 (packed in uint4) into a[0..7]
__device__ inline void add8(float* a, uint4 v){
  a[0] += bf2f((unsigned short)v.x); a[1] += bf2f((unsigned short)(v.x >> 16));
  a[2] += bf2f((unsigned short)v.y); a[3] += bf2f((unsigned short)(v.y >> 16));
  a[4] += bf2f((unsigned short)v.z); a[5] += bf2f((unsigned short)(v.z >> 16));
  a[6] += bf2f((unsigned short)v.w); a[7] += bf2f((unsigned short)(v.w >> 16));
}

// bijective XCD chunk swizzle (m204)
__device__ inline int xcd_swz(int bid, int nwg){
  int q = nwg >> 3, r = nwg & 7;
  int xcd = bid & 7, idx = bid >> 3;
  return (xcd < r ? xcd*(q+1) : r*(q+1) + (xcd-r)*q) + idx;
}

// ---------------- utility ----------------
__global__ void k_zeroi(int* p, int n){
  int i = blockIdx.x*256 + threadIdx.x;
  if (i < n) p[i] = 0;
}

// ---------------- CSR build ----------------
__global__ void k_hist(const int* __restrict__ dst, int E, int* deg){
  int e = blockIdx.x*256 + threadIdx.x;
  if (e < E) atomicAdd(&deg[dst[e]], 1);
}

__global__ __launch_bounds__(1024) void k_scan(int* degcur, int* __restrict__ rowptr, int n){
  __shared__ int wsum[16];
  __shared__ int carry;
  int tid = threadIdx.x, wid = tid >> 6, lane = tid & 63;
  if (tid == 0){ carry = 0; rowptr[0] = 0; }
  __syncthreads();
  for (int base = 0; base < n; base += 1024){
    int v = (base + tid < n) ? degcur[base + tid] : 0;
    int s = v;
#pragma unroll
    for (int off = 1; off < 64; off <<= 1){
      int t = __shfl_up(s, off);
      if (lane >= off) s += t;
    }
    if (lane == 63) wsum[wid] = s;
    __syncthreads();
    if (wid == 0 && lane < 16){
      int wv = wsum[lane];
#pragma unroll
      for (int off = 1; off < 16; off <<= 1){
        int t = __shfl_up(wv, off);
        if (lane >= off) wv += t;
      }
      wsum[lane] = wv;
    }
    __syncthreads();
    int incl = s + (wid ? wsum[wid-1] : 0) + carry;
    if (base + tid < n){ rowptr[base + tid + 1] = incl; degcur[base + tid] = incl - v; }
    __syncthreads();
    if (tid == 0) carry += wsum[15];
    __syncthreads();
  }
}

__global__ void k_scatter(const int* __restrict__ src, const int* __restrict__ dst,
                          int E, int* cursor, int* __restrict__ colsrc){
  int e = blockIdx.x*256 + threadIdx.x;
  if (e < E){
    int d = dst[e];
    int pos = atomicAdd(&cursor[d], 1);
    colsrc[pos] = src[e];
  }
}

// deterministic neighbor order: sort each node's segment ascending
__global__ void k_sortseg(const int* __restrict__ rowptr, int* __restrict__ colsrc, int n){
  int node = blockIdx.x*256 + threadIdx.x;
  if (node < n){
    int lo = rowptr[node], hi = rowptr[node+1];
    for (int i = lo + 1; i < hi; ++i){
      int v = colsrc[i];
      int j = i - 1;
      while (j >= lo && colsrc[j] > v){ colsrc[j+1] = colsrc[j]; --j; }
      colsrc[j+1] = v;
    }
  }
}

__global__ void k_gstart(const int* __restrict__ batch, int N, int* __restrict__ gstart){
  int g = blockIdx.x*256 + threadIdx.x;
  if (g <= NG){
    int lo = 0, hi = N;
    while (lo < hi){
      int mid = (lo + hi) >> 1;
      if (batch[mid] < g) lo = mid + 1; else hi = mid;
    }
    gstart[g] = lo;
  }
}

// ---- weight cast+transpose: W[k][n] f32 -> Wt[n][ldt] bf16 at column offset koff ----
__global__ void k_castT(const float* __restrict__ W, unsigned short* __restrict__ Wt,
                        int K, int Nn, int ldt, int koff){
  __shared__ float sh[32][33];
  const size_t in_off  = (size_t)blockIdx.z * K * Nn;
  const size_t out_off = (size_t)blockIdx.z * Nn * ldt;
  int n0 = blockIdx.x*32, k0 = blockIdx.y*32;
  int tx = threadIdx.x, ty = threadIdx.y;   // 32 x 8
  for (int r = ty; r < 32; r += 8)
    sh[r][tx] = W[in_off + (size_t)(k0 + r)*Nn + n0 + tx];
  __syncthreads();
  for (int r = ty; r < 32; r += 8)
    Wt[out_off + (size_t)(n0 + r)*ldt + koff + k0 + tx] = f2bf(sh[tx][r]);
}

__global__ void k_bias2(const float* __restrict__ a, const float* __restrict__ b,
                        float* __restrict__ o){
  int i = threadIdx.x;
  o[i] = a[i] + b[i];
}

// ---------------- pooling (applies BN2+ReLU in f32 from pre-BN2 values) ----------------
__global__ __launch_bounds__(320) void k_pool(const unsigned short* __restrict__ xpre,
                                              const float* __restrict__ bnsc2,
                                              const float* __restrict__ bnsf2,
                                              const int* __restrict__ gstart,
                                              float* __restrict__ pooled){
  int g = blockIdx.x;
  int t = threadIdx.x;              // handles feats 2t, 2t+1
  int f0 = 2*t;
  int l = f0 >> 7, c = f0 & 127;
  float sc0 = bnsc2[l*128 + c],     sf0 = bnsf2[l*128 + c];
  float sc1 = bnsc2[l*128 + c + 1], sf1 = bnsf2[l*128 + c + 1];
  int n0 = gstart[g], n1 = gstart[g+1];
  float a0 = 0.f, a1 = 0.f;
  for (int n = n0; n < n1; ++n){
    unsigned u = ((const unsigned*)xpre)[(size_t)n*(EMB/2) + t];
    a0 += fmaxf(fmaf(sc0, bf2f((unsigned short)u),        sf0), 0.f);
    a1 += fmaxf(fmaf(sc1, bf2f((unsigned short)(u >> 16)), sf1), 0.f);
  }
  *(float2*)(pooled + (size_t)g*EMB + 2*t) = make_float2(a0, a1);
}

__global__ __launch_bounds__(128) void k_pred(const float* __restrict__ pooled,
                                              const float* __restrict__ W,
                                              const float* __restrict__ b,
                                              float* __restrict__ xcat){
  int g = blockIdx.x, l = blockIdx.y, o = threadIdx.x;
  __shared__ float sh[128];
  sh[o] = pooled[(size_t)g*EMB + l*H + o];
  __syncthreads();
  const float* Wl = W + (size_t)l*H*H;
  float acc = b[l*H + o];
  for (int k = 0; k < H; ++k) acc = fmaf(sh[k], Wl[k*H + o], acc);
  xcat[(size_t)g*EMB + l*H + o] = acc;
}

// ---- bf16 MFMA GEMM, 128x128 tile, BK=64, depth-2 pipeline, RAW s_barrier ----
template<bool RELU, bool OUT_BF16, bool DUAL>
__global__ __launch_bounds__(512) void k_mm(
    const unsigned short* __restrict__ A, int lda,
    const unsigned short* __restrict__ A2,
    const unsigned short* __restrict__ Bt, int ldb,
    const float* __restrict__ bias,
    void* __restrict__ Cv, int ldc,
    int M, int K)
{
  __shared__ union LdsU {
    unsigned short stage[2][2][8192];
    unsigned short sc16[128*136];
    float          sc32[128*132];
  } u;
  const int tid  = threadIdx.x;
  const int lane = tid & 63;
  const int w    = tid >> 6;
  const int wr   = w >> 2, wc = w & 3;

  const int nwg = gridDim.x * gridDim.y;
  const int bid = blockIdx.y * gridDim.x + blockIdx.x;
  const int wg  = xcd_swz(bid, nwg);
  const int col0 = (wg % gridDim.x) * 128;
  const int row0 = (wg / gridDim.x) * 128;
  const int KA   = DUAL ? (K >> 1) : K;

  const unsigned short *sA[2], *sA2p[2], *sB[2];
  int dOff[2];
#pragma unroll
  for (int j = 0; j < 2; ++j){
    int d = w*2048 + j*1024 + lane*16;
    int m = d >> 7;
    int inner = (d & 127) ^ ((m & 7) << 4);
    int gm = row0 + m; if (gm > M-1) gm = M-1;
    sA[j]  = A + (size_t)gm*lda + (inner >> 1);
    if (DUAL) sA2p[j] = A2 + (size_t)gm*lda + (inner >> 1);
    sB[j]  = Bt + (size_t)(col0 + m)*ldb + (inner >> 1);
    dOff[j] = w*2048 + j*1024;
  }

  f32x4 acc[4][2];
#pragma unroll
  for (int i = 0; i < 4; ++i)
#pragma unroll
    for (int j = 0; j < 2; ++j)
      acc[i][j] = (f32x4){0.f, 0.f, 0.f, 0.f};

  auto STAGE = [&](int buf, int kt){
    int k0 = kt*64, ka = k0;
    bool second = DUAL && (k0 >= KA);
    if (second) ka = k0 - KA;
#pragma unroll
    for (int j = 0; j < 2; ++j){
      const unsigned short* s = second ? (sA2p[j] + ka) : (sA[j] + ka);
      __builtin_amdgcn_global_load_lds(
          (const __attribute__((address_space(1))) void*)s,
          (__attribute__((address_space(3))) void*)((char*)&u.stage[buf][0][0] + dOff[j]),
          16, 0, 0);
    }
#pragma unroll
    for (int j = 0; j < 2; ++j)
      __builtin_amdgcn_global_load_lds(
          (const __attribute__((address_space(1))) void*)(sB[j] + k0),
          (__attribute__((address_space(3))) void*)((char*)&u.stage[buf][1][0] + dOff[j]),
          16, 0, 0);
  };

  const int NT = K / 64;
  STAGE(0, 0);
  STAGE(1, 1);
  asm volatile("s_waitcnt vmcnt(4)" ::: "memory");
  asm volatile("s_barrier" ::: "memory");

  for (int t = 0; t < NT; ++t){
    const char* Ab = (const char*)&u.stage[t & 1][0][0];
    const char* Bb = (const char*)&u.stage[t & 1][1][0];
    bf16x8 af[2][4], bq[2][2];
#pragma unroll
    for (int kk = 0; kk < 2; ++kk){
      const int kb = kk*64 + ((lane >> 4) << 4);
#pragma unroll
      for (int i = 0; i < 4; ++i){
        int row = wr*64 + i*16 + (lane & 15);
        af[kk][i] = *(const bf16x8*)(Ab + ((row*128 + kb) ^ ((row & 7) << 4)));
      }
#pragma unroll
      for (int j = 0; j < 2; ++j){
        int col = wc*32 + j*16 + (lane & 15);
        bq[kk][j] = *(const bf16x8*)(Bb + ((col*128 + kb) ^ ((col & 7) << 4)));
      }
    }
    if (t + 2 < NT){
      asm volatile("s_barrier" ::: "memory");
      STAGE(t & 1, t + 2);
    }
#pragma unroll
    for (int kk = 0; kk < 2; ++kk)
#pragma unroll
      for (int i = 0; i < 4; ++i)
#pragma unroll
        for (int j = 0; j < 2; ++j)
          acc[i][j] = __builtin_amdgcn_mfma_f32_16x16x32_bf16(af[kk][i], bq[kk][j], acc[i][j], 0, 0, 0);
    if (t + 1 < NT){
      if (t + 2 < NT) asm volatile("s_waitcnt vmcnt(4)" ::: "memory");
      else            asm volatile("s_waitcnt vmcnt(0)" ::: "memory");
      asm volatile("s_barrier" ::: "memory");
    }
  }

  __syncthreads();
  if (OUT_BF16){
#pragma unroll
    for (int j = 0; j < 2; ++j){
      int cl = wc*32 + j*16 + (lane & 15);
      float bs = bias[col0 + cl];
#pragma unroll
      for (int i = 0; i < 4; ++i){
        int rb = wr*64 + i*16 + ((lane >> 4) << 2);
#pragma unroll
        for (int r = 0; r < 4; ++r){
          float v = acc[i][j][r] + bs;
          if (RELU) v = fmaxf(v, 0.f);
          u.sc16[(rb + r)*136 + cl] = f2bf(v);
        }
      }
    }
    __syncthreads();
    unsigned short* Cb = (unsigned short*)Cv;
    for (int idx = tid; idx < 128*16; idx += 512){
      int rr = idx >> 4, seg = idx & 15;
      int grow = row0 + rr;
      if (grow < M){
        uint4 vv = *(const uint4*)&u.sc16[rr*136 + seg*8];
        *(uint4*)(Cb + (size_t)grow*ldc + col0 + seg*8) = vv;
      }
    }
  } else {
#pragma unroll
    for (int j = 0; j < 2; ++j){
      int cl = wc*32 + j*16 + (lane & 15);
      float bs = bias[col0 + cl];
#pragma unroll
      for (int i = 0; i < 4; ++i){
        int rb = wr*64 + i*16 + ((lane >> 4) << 2);
#pragma unroll
        for (int r = 0; r < 4; ++r){
          float v = acc[i][j][r] + bs;
          if (RELU) v = fmaxf(v, 0.f);
          u.sc32[(rb + r)*132 + cl] = v;
        }
      }
    }
    __syncthreads();
    float* Cf = (float*)Cv;
    for (int idx = tid; idx < 128*32; idx += 512){
      int rr = idx >> 5, seg = idx & 31;
      int grow = row0 + rr;
      if (grow < M){
        float4 vv = *(const float4*)&u.sc32[rr*132 + seg*4];
        *(float4*)(Cf + (size_t)grow*ldc + col0 + seg*4) = vv;
      }
    }
  }
}

// ------- fused GIN-aggregate + conv GEMM1 + deterministic block stats -------
template<bool IN_BF16>
__global__ __launch_bounds__(512) void k_mmca(
    const void* __restrict__ hin, int ldh,
    const int* __restrict__ rowptr, const int* __restrict__ colsrc,
    const float* __restrict__ epsp,
    const unsigned short* __restrict__ Bt,
    const float* __restrict__ bias,
    unsigned short* __restrict__ C, int ldc,
    float* __restrict__ pa,
    int M)
{
  __shared__ unsigned short shm[2*128*128];
  __shared__ float sbs[2][128], sbq[2][128];
  unsigned short* As = shm;
  unsigned short* Bs = shm + 16384;
  const int tid  = threadIdx.x;
  const int lane = tid & 63;
  const int w    = tid >> 6;
  const int wr   = w >> 2, wc = w & 3;

  const int wg   = xcd_swz(blockIdx.x, gridDim.x);
  const int row0 = wg * 128;

#pragma unroll
  for (int j = 0; j < 4; ++j){
    int d = w*4096 + j*1024 + lane*16;
    int m = d >> 8;
    int inner = (d & 255) ^ ((m & 15) << 4);
    __builtin_amdgcn_global_load_lds(
        (const __attribute__((address_space(1))) void*)(Bt + (size_t)m*H + (inner >> 1)),
        (__attribute__((address_space(3))) void*)((char*)Bs + w*4096 + j*1024),
        16, 0, 0);
  }

  // gather A: thread handles row r = tid>>2, 32 cols at c0 = (tid&3)*32
  {
    int r  = tid >> 2;
    int c0 = (tid & 3) << 5;
    int node = row0 + r; if (node > M-1) node = M-1;
    float ep = 1.0f + *epsp;
    float a[32];
    if (IN_BF16){
      const unsigned short* src = (const unsigned short*)hin + (size_t)node*ldh + c0;
      uint4 v0 = *(const uint4*)(src);
      uint4 v1 = *(const uint4*)(src + 8);
      uint4 v2 = *(const uint4*)(src + 16);
      uint4 v3 = *(const uint4*)(src + 24);
#pragma unroll
      for (int q = 0; q < 32; ++q) a[q] = 0.f;
      add8(a,      v0); add8(a + 8,  v1); add8(a + 16, v2); add8(a + 24, v3);
#pragma unroll
      for (int q = 0; q < 32; ++q) a[q] *= ep;
    } else {
      const float* src = (const float*)hin + (size_t)node*ldh + c0;
#pragma unroll
      for (int q = 0; q < 32; q += 4){
        float4 f = *(const float4*)(src + q);
        a[q] = ep*f.x; a[q+1] = ep*f.y; a[q+2] = ep*f.z; a[q+3] = ep*f.w;
      }
    }
    int e = rowptr[node], e1 = rowptr[node+1];
    if (IN_BF16){
      for (; e + 2 <= e1; e += 2){            // 2 edges in flight (8 x 16B loads)
        int s0 = colsrc[e], s1 = colsrc[e+1];
        const unsigned short* p0 = (const unsigned short*)hin + (size_t)s0*ldh + c0;
        const unsigned short* p1 = (const unsigned short*)hin + (size_t)s1*ldh + c0;
        uint4 w0 = *(const uint4*)(p0);
        uint4 w1 = *(const uint4*)(p0 + 8);
        uint4 w2 = *(const uint4*)(p0 + 16);
        uint4 w3 = *(const uint4*)(p0 + 24);
        uint4 y0 = *(const uint4*)(p1);
        uint4 y1 = *(const uint4*)(p1 + 8);
        uint4 y2 = *(const uint4*)(p1 + 16);
        uint4 y3 = *(const uint4*)(p1 + 24);
        add8(a,      w0); add8(a + 8,  w1); add8(a + 16, w2); add8(a + 24, w3);
        add8(a,      y0); add8(a + 8,  y1); add8(a + 16, y2); add8(a + 24, y3);
      }
      for (; e < e1; ++e){
        int s = colsrc[e];
        const unsigned short* p = (const unsigned short*)hin + (size_t)s*ldh + c0;
        uint4 w0 = *(const uint4*)(p);
        uint4 w1 = *(const uint4*)(p + 8);
        uint4 w2 = *(const uint4*)(p + 16);
        uint4 w3 = *(const uint4*)(p + 24);
        add8(a,      w0); add8(a + 8,  w1); add8(a + 16, w2); add8(a + 24, w3);
      }
    } else {
      for (; e < e1; ++e){
        int s = colsrc[e];
        const float* p = (const float*)hin + (size_t)s*ldh + c0;
#pragma unroll
        for (int q = 0; q < 32; q += 4){
          float4 f = *(const float4*)(p + q);
          a[q] += f.x; a[q+1] += f.y; a[q+2] += f.z; a[q+3] += f.w;
        }
      }
    }
    // write 32 bf16 (64 B = 4 swizzled 16-B chunks) into As
#pragma unroll
    for (int q = 0; q < 4; ++q){
      unsigned pk[4];
#pragma unroll
      for (int k = 0; k < 4; ++k)
        pk[k] = (unsigned)f2bf(a[q*8 + 2*k]) | ((unsigned)f2bf(a[q*8 + 2*k + 1]) << 16);
      int byte = (r*256 + (tid & 3)*64 + q*16) ^ ((r & 15) << 4);
      *(uint4*)((char*)As + byte) = *(uint4*)pk;
    }
  }

  asm volatile("s_waitcnt vmcnt(0)" ::: "memory");
  __syncthreads();

  f32x4 acc[4][2];
#pragma unroll
  for (int i = 0; i < 4; ++i)
#pragma unroll
    for (int j = 0; j < 2; ++j)
      acc[i][j] = (f32x4){0.f, 0.f, 0.f, 0.f};

#pragma unroll
  for (int kk = 0; kk < 4; ++kk){
    const int kb = kk*64 + ((lane >> 4) << 4);
    bf16x8 af[4], bfr[2];
#pragma unroll
    for (int i = 0; i < 4; ++i){
      int row = wr*64 + i*16 + (lane & 15);
      af[i] = *(const bf16x8*)((const char*)As + ((row*256 + kb) ^ ((row & 15) << 4)));
    }
#pragma unroll
    for (int j = 0; j < 2; ++j){
      int col = wc*32 + j*16 + (lane & 15);
      bfr[j] = *(const bf16x8*)((const char*)Bs + ((col*256 + kb) ^ ((col & 15) << 4)));
    }
#pragma unroll
    for (int i = 0; i < 4; ++i)
#pragma unroll
      for (int j = 0; j < 2; ++j)
        acc[i][j] = __builtin_amdgcn_mfma_f32_16x16x32_bf16(af[i], bfr[j], acc[i][j], 0, 0, 0);
  }

  // deterministic block stats: wave partials -> LDS -> single combine -> pa
#pragma unroll
  for (int j = 0; j < 2; ++j){
    int col = wc*32 + j*16 + (lane & 15);
    float bs = bias[col];
    float s = 0.f, q = 0.f;
#pragma unroll
    for (int i = 0; i < 4; ++i){
      int rb = row0 + wr*64 + i*16 + ((lane >> 4) << 2);
#pragma unroll
      for (int r = 0; r < 4; ++r){
        if (rb + r < M){
          float v = acc[i][j][r] + bs;
          s += v; q += v*v;
        }
      }
    }
    s += __shfl_xor(s, 16); q += __shfl_xor(q, 16);
    s += __shfl_xor(s, 32); q += __shfl_xor(q, 32);
    if (lane < 16){ sbs[wr][col] = s; sbq[wr][col] = q; }
  }
  __syncthreads();
  if (tid < 128){
    pa[(size_t)wg*256 + tid]       = sbs[0][tid] + sbs[1][tid];
    pa[(size_t)wg*256 + 128 + tid] = sbq[0][tid] + sbq[1][tid];
  }

  // epilogue: transpose via LDS (staging dead), coalesced 16-B stores
  __syncthreads();
#pragma unroll
  for (int j = 0; j < 2; ++j){
    int cl = wc*32 + j*16 + (lane & 15);
    float bs = bias[cl];
#pragma unroll
    for (int i = 0; i < 4; ++i){
      int rb = wr*64 + i*16 + ((lane >> 4) << 2);
#pragma unroll
      for (int r = 0; r < 4; ++r)
        shm[(rb + r)*136 + cl] = f2bf(acc[i][j][r] + bs);
    }
  }
  __syncthreads();
  for (int idx = tid; idx < 128*16; idx += 512){
    int rr = idx >> 4, seg = idx & 15;
    int grow = row0 + rr;
    if (grow < M){
      uint4 vv = *(const uint4*)&shm[rr*136 + seg*8];
      *(uint4*)(C + (size_t)grow*ldc + seg*8) = vv;
    }
  }
}

// ------- conv GEMM2: BN1 scale/shift from global (precomputed) + block stats to pb -------
__global__ __launch_bounds__(512) void k_mmc2(
    const unsigned short* __restrict__ A,     // [M][128] bf16 (pre-BN1)
    const unsigned short* __restrict__ Bt,
    const float* __restrict__ bias,
    const float* __restrict__ sc1, const float* __restrict__ sf1,  // BN1 scale/shift
    unsigned short* __restrict__ C, int ldc,
    float* __restrict__ pb,                   // [nwg][256] BN2 partials
    int M)
{
  __shared__ unsigned short shm[2*128*128];
  __shared__ float bnsc[128], bnsf[128];
  __shared__ float rs[2][128], rq[2][128];
  unsigned short* As = shm;
  unsigned short* Bs = shm + 16384;
  const int tid  = threadIdx.x;
  const int lane = tid & 63;
  const int w    = tid >> 6;
  const int wr   = w >> 2, wc = w & 3;
  const int nwg  = gridDim.x;

  const int wg   = xcd_swz(blockIdx.x, nwg);
  const int row0 = wg * 128;

#pragma unroll
  for (int j = 0; j < 4; ++j){
    int d = w*4096 + j*1024 + lane*16;
    int m = d >> 8;
    int inner = (d & 255) ^ ((m & 15) << 4);
    int gm = row0 + m; if (gm > M-1) gm = M-1;
    __builtin_amdgcn_global_load_lds(
        (const __attribute__((address_space(1))) void*)(A + (size_t)gm*H + (inner >> 1)),
        (__attribute__((address_space(3))) void*)((char*)As + w*4096 + j*1024),
        16, 0, 0);
    __builtin_amdgcn_global_load_lds(
        (const __attribute__((address_space(1))) void*)(Bt + (size_t)m*H + (inner >> 1)),
        (__attribute__((address_space(3))) void*)((char*)Bs + w*4096 + j*1024),
        16, 0, 0);
  }

  // BN1 scale/shift: plain load (overlaps with staging)
  if (tid < 128){
    bnsc[tid] = sc1[tid];
    bnsf[tid] = sf1[tid];
  }

  asm volatile("s_waitcnt vmcnt(0)" ::: "memory");
  __syncthreads();

  f32x4 acc[4][2];
#pragma unroll
  for (int i = 0; i < 4; ++i)
#pragma unroll
    for (int j = 0; j < 2; ++j)
      acc[i][j] = (f32x4){0.f, 0.f, 0.f, 0.f};

#pragma unroll
  for (int kk = 0; kk < 4; ++kk){
    const int kb = kk*64 + ((lane >> 4) << 4);
    bf16x8 af[4], bfr[2];
#pragma unroll
    for (int i = 0; i < 4; ++i){
      int row = wr*64 + i*16 + (lane & 15);
      af[i] = *(const bf16x8*)((const char*)As + ((row*256 + kb) ^ ((row & 15) << 4)));
    }
#pragma unroll
    for (int j = 0; j < 2; ++j){
      int col = wc*32 + j*16 + (lane & 15);
      bfr[j] = *(const bf16x8*)((const char*)Bs + ((col*256 + kb) ^ ((col & 15) << 4)));
    }
    {
      int k8 = kk*32 + ((lane >> 4) << 3);
      float4 s0 = *(const float4*)(&bnsc[k8]), s1 = *(const float4*)(&bnsc[k8 + 4]);
      float4 f0 = *(const float4*)(&bnsf[k8]), f1 = *(const float4*)(&bnsf[k8 + 4]);
      float sc[8] = {s0.x,s0.y,s0.z,s0.w,s1.x,s1.y,s1.z,s1.w};
      float sf[8] = {f0.x,f0.y,f0.z,f0.w,f1.x,f1.y,f1.z,f1.w};
#pragma unroll
      for (int i = 0; i < 4; ++i){
        bf16x8 aa = af[i], o;
#pragma unroll
        for (int jj = 0; jj < 8; ++jj){
          float v = fmaxf(fmaf(sc[jj], bf2f((unsigned short)aa[jj]), sf[jj]), 0.f);
          o[jj] = (short)f2bf(v);
        }
        af[i] = o;
      }
    }
#pragma unroll
    for (int i = 0; i < 4; ++i)
#pragma unroll
      for (int j = 0; j < 2; ++j)
        acc[i][j] = __builtin_amdgcn_mfma_f32_16x16x32_bf16(af[i], bfr[j], acc[i][j], 0, 0, 0);
  }

  // deterministic block stats -> pb
#pragma unroll
  for (int j = 0; j < 2; ++j){
    int col = wc*32 + j*16 + (lane & 15);
    float bs = bias[col];
    float s = 0.f, q = 0.f;
#pragma unroll
    for (int i = 0; i < 4; ++i){
      int rb = row0 + wr*64 + i*16 + ((lane >> 4) << 2);
#pragma unroll
      for (int r = 0; r < 4; ++r){
        if (rb + r < M){
          float v = acc[i][j][r] + bs;
          s += v; q += v*v;
        }
      }
    }
    s += __shfl_xor(s, 16); q += __shfl_xor(q, 16);
    s += __shfl_xor(s, 32); q += __shfl_xor(q, 32);
    if (lane < 16){ rs[wr][col] = s; rq[wr][col] = q; }
  }
  __syncthreads();
  if (tid < 128){
    pb[(size_t)wg*256 + tid]       = rs[0][tid] + rs[1][tid];
    pb[(size_t)wg*256 + 128 + tid] = rq[0][tid] + rq[1][tid];
  }

  __syncthreads();
#pragma unroll
  for (int j = 0; j < 2; ++j){
    int cl = wc*32 + j*16 + (lane & 15);
    float bs = bias[cl];
#pragma unroll
    for (int i = 0; i < 4; ++i){
      int rb = wr*64 + i*16 + ((lane >> 4) << 2);
#pragma unroll
      for (int r = 0; r < 4; ++r)
        shm[(rb + r)*136 + cl] = f2bf(acc[i][j][r] + bs);
    }
  }
  __syncthreads();
  for (int idx = tid; idx < 128*16; idx += 512){
    int rr = idx >> 4, seg = idx & 15;
    int grow = row0 + rr;
    if (grow < M){
      uint4 vv = *(const uint4*)&shm[rr*136 + seg*8];
      *(uint4*)(C + (size_t)grow*ldc + seg*8) = vv;
    }
  }
}

// ---- BN finalize: one block per channel, fixed-tree deterministic reduction ----
__global__ __launch_bounds__(128) void k_bnfin2(const float* __restrict__ pp,
                                                const float* __restrict__ g,
                                                const float* __restrict__ b,
                                                float* __restrict__ scale,
                                                float* __restrict__ shift,
                                                float invn, int nwg){
  __shared__ float ss[128], qq[128];
  int c = blockIdx.x;      // channel 0..127
  int j = threadIdx.x;     // 0..127
  float s = 0.f, q = 0.f;
  for (int bi = j; bi < nwg; bi += 128){
    s += pp[(size_t)bi*256 + c];
    q += pp[(size_t)bi*256 + 128 + c];
  }
  ss[j] = s; qq[j] = q;
  __syncthreads();
#pragma unroll
  for (int off = 64; off > 0; off >>= 1){
    if (j < off){ ss[j] += ss[j+off]; qq[j] += qq[j+off]; }
    __syncthreads();
  }
  if (j == 0){
    float m = ss[0]*invn;
    float v = qq[0]*invn - m*m;
    float inv = rsqrtf(v + BN_EPS);
    float sc = g[c]*inv;
    scale[c] = sc;
    shift[c] = b[c] - m*sc;
  }
}

// ---- BN2 apply: out = bf16(relu(sc*U+sf)), U stride ldu ----
__global__ __launch_bounds__(256) void k_bnapply(const unsigned short* __restrict__ U,
                                                 int ldu,
                                                 const float* __restrict__ scale,
                                                 const float* __restrict__ shift,
                                                 unsigned short* __restrict__ out,
                                                 int ldo, int n){
  int i = blockIdx.x*256 + threadIdx.x;
  int total = n * (H/4);
  if (i < total){
    int r = i >> 5;
    int c4 = (i & 31) << 2;
    uint2 up = *(const uint2*)(U + (size_t)r*ldu + c4);
    float4 sc = *(const float4*)(scale + c4);
    float4 sf = *(const float4*)(shift + c4);
    float a = fmaxf(fmaf(sc.x, bf2f((unsigned short)up.x),       sf.x), 0.f);
    float c = fmaxf(fmaf(sc.y, bf2f((unsigned short)(up.x>>16)), sf.y), 0.f);
    float d = fmaxf(fmaf(sc.z, bf2f((unsigned short)up.y),       sf.z), 0.f);
    float e = fmaxf(fmaf(sc.w, bf2f((unsigned short)(up.y>>16)), sf.w), 0.f);
    uint2 o;
    o.x = (unsigned)f2bf(a) | ((unsigned)f2bf(c) << 16);
    o.y = (unsigned)f2bf(d) | ((unsigned)f2bf(e) << 16);
    *(uint2*)(out + (size_t)r*ldo + c4) = o;
  }
}

// ---------------- f32 GEMM 32x64 tile (graph FF, M=512) ----------------
template<bool RELU, bool ADD_D>
__global__ __launch_bounds__(256) void k_gemm64(
    const float* __restrict__ A, int lda,
    const float* __restrict__ B, int ldb,
    const float* __restrict__ bias,
    const float* D, int ldd,
    float* C, int ldc,
    int M, int N, int K)
{
  __shared__ float As[32][36];
  __shared__ float Bs[32][64];
  const int tid  = threadIdx.x;
  const int tx   = tid & 15;
  const int ty   = tid >> 4;
  const int row0 = blockIdx.x * 32;
  const int col0 = blockIdx.y * 64;
  const int am = tid >> 3;
  const int ak = (tid & 7) << 2;
  const int bk = tid >> 4;
  const int bn = (tid & 15) << 2;
  float acc[2][4] = {};

  for (int k0 = 0; k0 < K; k0 += 32){
    {
      int gr = row0 + am;
      float4 v = make_float4(0.f, 0.f, 0.f, 0.f);
      if (gr < M) v = *(const float4*)(A + (size_t)gr*lda + k0 + ak);
      As[ak+0][am]=v.x; As[ak+1][am]=v.y; As[ak+2][am]=v.z; As[ak+3][am]=v.w;
    }
#pragma unroll
    for (int h = 0; h < 2; ++h){
      int kk = bk + h*16;
      *(float4*)(&Bs[kk][bn]) = *(const float4*)(B + (size_t)(k0+kk)*ldb + col0 + bn);
    }
    __syncthreads();
#pragma unroll 8
    for (int k = 0; k < 32; ++k){
      float2 a = *(const float2*)(&As[k][ty<<1]);
      float4 b = *(const float4*)(&Bs[k][tx<<2]);
      float av[2] = {a.x, a.y};
      float bv[4] = {b.x, b.y, b.z, b.w};
#pragma unroll
      for (int i = 0; i < 2; ++i)
#pragma unroll
        for (int j = 0; j < 4; ++j)
          acc[i][j] = fmaf(av[i], bv[j], acc[i][j]);
    }
    __syncthreads();
  }

  const int col = col0 + (tx<<2);
  float4 bv = *(const float4*)(bias + col);
#pragma unroll
  for (int i = 0; i < 2; ++i){
    int row = row0 + (ty<<1) + i;
    if (row < M){
      float r[4] = {acc[i][0]+bv.x, acc[i][1]+bv.y, acc[i][2]+bv.z, acc[i][3]+bv.w};
      if (RELU){
#pragma unroll
        for (int j = 0; j < 4; ++j) r[j] = fmaxf(r[j], 0.f);
      }
      if (ADD_D){
        float4 d = *(const float4*)(D + (size_t)row*ldd + col);
        r[0]+=d.x; r[1]+=d.y; r[2]+=d.z; r[3]+=d.w;
      }
      *(float4*)(C + (size_t)row*ldc + col) = make_float4(r[0],r[1],r[2],r[3]);
    }
  }
}

// ---------------- host ----------------
extern "C" void kernel_launch(void* const* d_in, const int* in_sizes, int n_in,
                              void* d_out, int out_size, void* d_ws, size_t ws_size,
                              hipStream_t stream) {
  const float* x        = (const float*)d_in[0];
  const int*   ei       = (const int*)d_in[1];
  const int*   batch    = (const int*)d_in[2];
  const float* conv_W1  = (const float*)d_in[3];
  const float* conv_b1  = (const float*)d_in[4];
  const float* conv_g1  = (const float*)d_in[5];
  const float* conv_be1 = (const float*)d_in[6];
  const float* conv_W2  = (const float*)d_in[7];
  const float* conv_b2  = (const float*)d_in[8];
  const float* epsv     = (const float*)d_in[9];
  const float* bn_g     = (const float*)d_in[10];
  const float* bn_b     = (const float*)d_in[11];
  const float* pred_W   = (const float*)d_in[12];
  const float* pred_b   = (const float*)d_in[13];
  const float* gW       = (const float*)d_in[14];
  const float* gb       = (const float*)d_in[15];
  const float* gsW      = (const float*)d_in[16];
  const float* gsb      = (const float*)d_in[17];
  const float* lW       = (const float*)d_in[18];
  const float* lb       = (const float*)d_in[19];
  const float* lsW      = (const float*)d_in[20];
  const float* lsb      = (const float*)d_in[21];

  const int N = in_sizes[0] / H;
  const int E = in_sizes[1] / 2;
  const int* srcI = ei;
  const int* dstI = ei + E;

  float* out = (float*)d_out;
  float* GE = out;                              // [NG][EMB]
  float* NE = out + (size_t)NG*EMB;             // [N][EMB] f32
  float* XC = NE + (size_t)N*EMB;               // [NG][EMB]

  // ---- workspace layout ----
  unsigned short* xall = (unsigned short*)d_ws;             // [N][EMB] bf16 (post-BN2)
  unsigned short* h1   = xall + (size_t)N*EMB;              // [N][EMB] bf16
  unsigned short* h2   = h1 + (size_t)N*EMB;                // [N][EMB] bf16
  unsigned short* ub   = h1;                                // [N][H] (alias, conv loop)
  unsigned short* xpre = h2;                                // [N][EMB] pre-BN2 (h2 reused after pool)

  float* pooled  = (float*)(h2 + (size_t)N*EMB);            // [NG][EMB]
  float* gtmp1   = pooled + (size_t)NG*EMB;
  float* gtmp2   = gtmp1 + (size_t)NG*EMB;
  const int nrow = (N + 127)/128;                           // 391
  float* pa      = gtmp2 + (size_t)NG*EMB;                  // [nrow][256] BN1 partials
  float* pb      = pa + (size_t)nrow*256;                   // [nrow][256] BN2 partials
  float* bnsc2   = pb + (size_t)nrow*256;                   // [5][128]
  float* bnsf2   = bnsc2 + LNUM*128;                        // [5][128]
  float* bnsc1   = bnsf2 + LNUM*128;                        // [128]
  float* bnsf1   = bnsc1 + 128;                             // [128]
  float* biasNE  = bnsf1 + 128;                             // [640]
  unsigned short* W1t   = (unsigned short*)(biasNE + EMB);  // [L][H][H]
  unsigned short* W2t   = W1t + (size_t)LNUM*H*H;
  unsigned short* lWt01 = W2t + (size_t)LNUM*H*H;           // [2][EMB][EMB]
  unsigned short* Wcat  = lWt01 + (size_t)2*EMB*EMB;        // [EMB][2*EMB]
  int* rowptr = (int*)(Wcat + (size_t)2*EMB*EMB);           // [N+1]
  int* cursor = rowptr + (N + 1);                           // [N]
  int* colsrc = cursor + N;                                 // [E]
  int* gstart = colsrc + E;                                 // [NG+1]

  // CSR build (deterministic: segments sorted after scatter)
  k_zeroi<<<(N+255)/256, 256, 0, stream>>>(cursor, N);
  k_hist<<<(E+255)/256, 256, 0, stream>>>(dstI, E, cursor);
  k_scan<<<1, 1024, 0, stream>>>(cursor, rowptr, N);
  k_scatter<<<(E+255)/256, 256, 0, stream>>>(srcI, dstI, E, cursor, colsrc);
  k_sortseg<<<(N+255)/256, 256, 0, stream>>>(rowptr, colsrc, N);
  k_gstart<<<(NG+256)/256, 256, 0, stream>>>(batch, N, gstart);

  // weights -> bf16 transposed [n][k]
  const dim3 tb32(32, 8);
  k_castT<<<dim3(H/32, H/32, LNUM), tb32, 0, stream>>>(conv_W1, W1t, H, H, H, 0);
  k_castT<<<dim3(H/32, H/32, LNUM), tb32, 0, stream>>>(conv_W2, W2t, H, H, H, 0);
  k_castT<<<dim3(EMB/32, EMB/32, 2), tb32, 0, stream>>>(lW, lWt01, EMB, EMB, EMB, 0);
  k_castT<<<dim3(EMB/32, EMB/32, 1), tb32, 0, stream>>>(lW + (size_t)2*EMB*EMB, Wcat,
                                                        EMB, EMB, 2*EMB, 0);
  k_castT<<<dim3(EMB/32, EMB/32, 1), tb32, 0, stream>>>(lsW, Wcat, EMB, EMB, 2*EMB, EMB);
  k_bias2<<<1, EMB, 0, stream>>>(lb + (size_t)2*EMB, lsb, biasNE);

  const float invn = 1.0f / (float)N;

  for (int l = 0; l < LNUM; ++l){
    // ub = agg(h) @ W1 + b1  (fused gather; bf16 out; BN1 partials -> pa)
    if (l == 0)
      k_mmca<false><<<nrow, 512, 0, stream>>>(
          x, H, rowptr, colsrc, epsv, W1t, conv_b1, ub, H, pa, N);
    else
      k_mmca<true><<<nrow, 512, 0, stream>>>(
          xall + (size_t)(l-1)*H, EMB, rowptr, colsrc, epsv + l,
          W1t + (size_t)l*H*H, conv_b1 + l*H, ub, H, pa, N);

    // BN1 finalize (parallel, deterministic fixed-tree)
    k_bnfin2<<<128, 128, 0, stream>>>(pa, conv_g1 + l*H, conv_be1 + l*H,
                                      bnsc1, bnsf1, invn, nrow);

    // xpre[:,l*H:] = relu(bn1(ub)) @ W2 + b2  (BN2 partials -> pb)
    k_mmc2<<<nrow, 512, 0, stream>>>(
        ub, W2t + (size_t)l*H*H, conv_b2 + l*H,
        bnsc1, bnsf1,
        xpre + (size_t)l*H, EMB, pb, N);

    // BN2 finalize -> per-layer scale/shift (parallel, deterministic)
    k_bnfin2<<<128, 128, 0, stream>>>(pb, bn_g + l*H, bn_b + l*H,
                                      bnsc2 + l*128, bnsf2 + l*128, invn, nrow);

    // xall[:,l*H:] = bf16(relu(bn2(xpre)))
    k_bnapply<<<(N*32 + 255)/256, 256, 0, stream>>>(
        xpre + (size_t)l*H, EMB, bnsc2 + l*128, bnsf2 + l*128,
        xall + (size_t)l*H, EMB, N);
  }

  // pooling (BN2 applied in f32 from xpre) + prediction heads -> xcat
  k_pool<<<NG, 320, 0, stream>>>(xpre, bnsc2, bnsf2, gstart, pooled);
  k_pred<<<dim3(NG, LNUM), 128, 0, stream>>>(pooled, pred_W, pred_b, XC);

  // graph FF (f32, M=512): GE = relu-chain(XC) + XC @ gsW + gsb
  const dim3 gg((NG + 31)/32, EMB/64);          // (16, 10)
  k_gemm64<false,false><<<gg, 256, 0, stream>>>(XC, EMB, gsW, EMB, gsb,
                                                nullptr, 0, GE, EMB, NG, EMB, EMB);
  k_gemm64<true,false><<<gg, 256, 0, stream>>>(XC, EMB, gW, EMB, gb,
                                               nullptr, 0, gtmp1, EMB, NG, EMB, EMB);
  k_gemm64<true,false><<<gg, 256, 0, stream>>>(gtmp1, EMB, gW + (size_t)EMB*EMB, EMB, gb + EMB,
                                               nullptr, 0, gtmp2, EMB, NG, EMB, EMB);
  k_gemm64<true,true><<<gg, 256, 0, stream>>>(gtmp2, EMB, gW + (size_t)2*EMB*EMB, EMB, gb + 2*EMB,
                                              GE, EMB, GE, EMB, NG, EMB, EMB);

  // node FF (bf16 MFMA, 128x128 tile, depth-2 raw-barrier pipeline, XCD swizzle):
  const dim3 gn(EMB/128, nrow);                 // (5, 391)
  // h1 = relu(xall @ lW0 + lb0)
  k_mm<true,true,false><<<gn, 512, 0, stream>>>(
      xall, EMB, nullptr, lWt01, EMB, lb, h1, EMB, N, EMB);
  // h2 = relu(h1 @ lW1 + lb1)   (h2 aliases xpre — pool already consumed it)
  k_mm<true,true,false><<<gn, 512, 0, stream>>>(
      h1, EMB, nullptr, lWt01 + (size_t)EMB*EMB, EMB, lb + EMB, h2, EMB, N, EMB);
  // NE = [h2 | xall] @ [lW2 ; lsW] + (lb2 + lsb)   (dual-A, K=1280, f32 out)
  k_mm<false,false,true><<<gn, 512, 0, stream>>>(
      h2, EMB, xall, Wcat, 2*EMB, biasNE, NE, EMB, N, 2*EMB);
}

// Round 16
// 1015.343 us; speedup vs baseline: 1.4895x; 1.0033x over previous
//
#include <hip/hip_runtime.h>

constexpr int H    = 128;
constexpr int LNUM = 5;
constexpr int NG   = 512;
constexpr int EMB  = 640;   // LNUM * H
constexpr float BN_EPS = 1e-5f;

typedef __attribute__((ext_vector_type(8))) short bf16x8;
typedef __attribute__((ext_vector_type(4))) float f32x4;

__device__ inline unsigned short f2bf(float f){
  unsigned u = __builtin_bit_cast(unsigned, f);
  u += 0x7FFF + ((u >> 16) & 1);
  return (unsigned short)(u >> 16);
}
__device__ inline float bf2f(unsigned short h){
  unsigned u = ((unsigned)h) << 16;
  return __builtin_bit_cast(float, u);
}

// accumulate 8 bf16 (packed in uint4) into a[0..7]
__device__ inline void add8(float* a, uint4 v){
  a[0] += bf2f((unsigned short)v.x); a[1] += bf2f((unsigned short)(v.x >> 16));
  a[2] += bf2f((unsigned short)v.y); a[3] += bf2f((unsigned short)(v.y >> 16));
  a[4] += bf2f((unsigned short)v.z); a[5] += bf2f((unsigned short)(v.z >> 16));
  a[6] += bf2f((unsigned short)v.w); a[7] += bf2f((unsigned short)(v.w >> 16));
}

// bijective XCD chunk swizzle (m204)
__device__ inline int xcd_swz(int bid, int nwg){
  int q = nwg >> 3, r = nwg & 7;
  int xcd = bid & 7, idx = bid >> 3;
  return (xcd < r ? xcd*(q+1) : r*(q+1) + (xcd-r)*q) + idx;
}

// ---------------- utility ----------------
__global__ void k_zeroi(int* p, int n){
  int i = blockIdx.x*256 + threadIdx.x;
  if (i < n) p[i] = 0;
}

// ---------------- CSR build ----------------
__global__ void k_hist(const int* __restrict__ dst, int E, int* deg){
  int e = blockIdx.x*256 + threadIdx.x;
  if (e < E) atomicAdd(&deg[dst[e]], 1);
}

__global__ __launch_bounds__(1024) void k_scan(int* degcur, int* __restrict__ rowptr, int n){
  __shared__ int wsum[16];
  __shared__ int carry;
  int tid = threadIdx.x, wid = tid >> 6, lane = tid & 63;
  if (tid == 0){ carry = 0; rowptr[0] = 0; }
  __syncthreads();
  for (int base = 0; base < n; base += 1024){
    int v = (base + tid < n) ? degcur[base + tid] : 0;
    int s = v;
#pragma unroll
    for (int off = 1; off < 64; off <<= 1){
      int t = __shfl_up(s, off);
      if (lane >= off) s += t;
    }
    if (lane == 63) wsum[wid] = s;
    __syncthreads();
    if (wid == 0 && lane < 16){
      int wv = wsum[lane];
#pragma unroll
      for (int off = 1; off < 16; off <<= 1){
        int t = __shfl_up(wv, off);
        if (lane >= off) wv += t;
      }
      wsum[lane] = wv;
    }
    __syncthreads();
    int incl = s + (wid ? wsum[wid-1] : 0) + carry;
    if (base + tid < n){ rowptr[base + tid + 1] = incl; degcur[base + tid] = incl - v; }
    __syncthreads();
    if (tid == 0) carry += wsum[15];
    __syncthreads();
  }
}

__global__ void k_scatter(const int* __restrict__ src, const int* __restrict__ dst,
                          int E, int* cursor, int* __restrict__ colsrc){
  int e = blockIdx.x*256 + threadIdx.x;
  if (e < E){
    int d = dst[e];
    int pos = atomicAdd(&cursor[d], 1);
    colsrc[pos] = src[e];
  }
}

// deterministic neighbor order: sort each node's segment ascending
__global__ void k_sortseg(const int* __restrict__ rowptr, int* __restrict__ colsrc, int n){
  int node = blockIdx.x*256 + threadIdx.x;
  if (node < n){
    int lo = rowptr[node], hi = rowptr[node+1];
    for (int i = lo + 1; i < hi; ++i){
      int v = colsrc[i];
      int j = i - 1;
      while (j >= lo && colsrc[j] > v){ colsrc[j+1] = colsrc[j]; --j; }
      colsrc[j+1] = v;
    }
  }
}

__global__ void k_gstart(const int* __restrict__ batch, int N, int* __restrict__ gstart){
  int g = blockIdx.x*256 + threadIdx.x;
  if (g <= NG){
    int lo = 0, hi = N;
    while (lo < hi){
      int mid = (lo + hi) >> 1;
      if (batch[mid] < g) lo = mid + 1; else hi = mid;
    }
    gstart[g] = lo;
  }
}

// ---- weight cast+transpose: W[k][n] f32 -> Wt[n][ldt] bf16 at column offset koff ----
__global__ void k_castT(const float* __restrict__ W, unsigned short* __restrict__ Wt,
                        int K, int Nn, int ldt, int koff){
  __shared__ float sh[32][33];
  const size_t in_off  = (size_t)blockIdx.z * K * Nn;
  const size_t out_off = (size_t)blockIdx.z * Nn * ldt;
  int n0 = blockIdx.x*32, k0 = blockIdx.y*32;
  int tx = threadIdx.x, ty = threadIdx.y;   // 32 x 8
  for (int r = ty; r < 32; r += 8)
    sh[r][tx] = W[in_off + (size_t)(k0 + r)*Nn + n0 + tx];
  __syncthreads();
  for (int r = ty; r < 32; r += 8)
    Wt[out_off + (size_t)(n0 + r)*ldt + koff + k0 + tx] = f2bf(sh[tx][r]);
}

__global__ void k_bias2(const float* __restrict__ a, const float* __restrict__ b,
                        float* __restrict__ o){
  int i = threadIdx.x;
  o[i] = a[i] + b[i];
}

// ---------------- pooling (applies BN2+ReLU in f32 from pre-BN2 values) ----------------
__global__ __launch_bounds__(320) void k_pool(const unsigned short* __restrict__ xpre,
                                              const float* __restrict__ bnsc2,
                                              const float* __restrict__ bnsf2,
                                              const int* __restrict__ gstart,
                                              float* __restrict__ pooled){
  int g = blockIdx.x;
  int t = threadIdx.x;              // handles feats 2t, 2t+1
  int f0 = 2*t;
  int l = f0 >> 7, c = f0 & 127;
  float sc0 = bnsc2[l*128 + c],     sf0 = bnsf2[l*128 + c];
  float sc1 = bnsc2[l*128 + c + 1], sf1 = bnsf2[l*128 + c + 1];
  int n0 = gstart[g], n1 = gstart[g+1];
  float a0 = 0.f, a1 = 0.f;
  for (int n = n0; n < n1; ++n){
    unsigned u = ((const unsigned*)xpre)[(size_t)n*(EMB/2) + t];
    a0 += fmaxf(fmaf(sc0, bf2f((unsigned short)u),        sf0), 0.f);
    a1 += fmaxf(fmaf(sc1, bf2f((unsigned short)(u >> 16)), sf1), 0.f);
  }
  *(float2*)(pooled + (size_t)g*EMB + 2*t) = make_float2(a0, a1);
}

__global__ __launch_bounds__(128) void k_pred(const float* __restrict__ pooled,
                                              const float* __restrict__ W,
                                              const float* __restrict__ b,
                                              float* __restrict__ xcat){
  int g = blockIdx.x, l = blockIdx.y, o = threadIdx.x;
  __shared__ float sh[128];
  sh[o] = pooled[(size_t)g*EMB + l*H + o];
  __syncthreads();
  const float* Wl = W + (size_t)l*H*H;
  float acc = b[l*H + o];
  for (int k = 0; k < H; ++k) acc = fmaf(sh[k], Wl[k*H + o], acc);
  xcat[(size_t)g*EMB + l*H + o] = acc;
}

// ---- bf16 MFMA GEMM, 128x128 tile, BK=64, depth-2 pipeline, RAW s_barrier ----
template<bool RELU, bool OUT_BF16, bool DUAL>
__global__ __launch_bounds__(512) void k_mm(
    const unsigned short* __restrict__ A, int lda,
    const unsigned short* __restrict__ A2,
    const unsigned short* __restrict__ Bt, int ldb,
    const float* __restrict__ bias,
    void* __restrict__ Cv, int ldc,
    int M, int K)
{
  __shared__ union LdsU {
    unsigned short stage[2][2][8192];
    unsigned short sc16[128*136];
    float          sc32[128*132];
  } u;
  const int tid  = threadIdx.x;
  const int lane = tid & 63;
  const int w    = tid >> 6;
  const int wr   = w >> 2, wc = w & 3;

  const int nwg = gridDim.x * gridDim.y;
  const int bid = blockIdx.y * gridDim.x + blockIdx.x;
  const int wg  = xcd_swz(bid, nwg);
  const int col0 = (wg % gridDim.x) * 128;
  const int row0 = (wg / gridDim.x) * 128;
  const int KA   = DUAL ? (K >> 1) : K;

  const unsigned short *sA[2], *sA2p[2], *sB[2];
  int dOff[2];
#pragma unroll
  for (int j = 0; j < 2; ++j){
    int d = w*2048 + j*1024 + lane*16;
    int m = d >> 7;
    int inner = (d & 127) ^ ((m & 7) << 4);
    int gm = row0 + m; if (gm > M-1) gm = M-1;
    sA[j]  = A + (size_t)gm*lda + (inner >> 1);
    if (DUAL) sA2p[j] = A2 + (size_t)gm*lda + (inner >> 1);
    sB[j]  = Bt + (size_t)(col0 + m)*ldb + (inner >> 1);
    dOff[j] = w*2048 + j*1024;
  }

  f32x4 acc[4][2];
#pragma unroll
  for (int i = 0; i < 4; ++i)
#pragma unroll
    for (int j = 0; j < 2; ++j)
      acc[i][j] = (f32x4){0.f, 0.f, 0.f, 0.f};

  auto STAGE = [&](int buf, int kt){
    int k0 = kt*64, ka = k0;
    bool second = DUAL && (k0 >= KA);
    if (second) ka = k0 - KA;
#pragma unroll
    for (int j = 0; j < 2; ++j){
      const unsigned short* s = second ? (sA2p[j] + ka) : (sA[j] + ka);
      __builtin_amdgcn_global_load_lds(
          (const __attribute__((address_space(1))) void*)s,
          (__attribute__((address_space(3))) void*)((char*)&u.stage[buf][0][0] + dOff[j]),
          16, 0, 0);
    }
#pragma unroll
    for (int j = 0; j < 2; ++j)
      __builtin_amdgcn_global_load_lds(
          (const __attribute__((address_space(1))) void*)(sB[j] + k0),
          (__attribute__((address_space(3))) void*)((char*)&u.stage[buf][1][0] + dOff[j]),
          16, 0, 0);
  };

  const int NT = K / 64;
  STAGE(0, 0);
  STAGE(1, 1);
  asm volatile("s_waitcnt vmcnt(4)" ::: "memory");
  asm volatile("s_barrier" ::: "memory");

  for (int t = 0; t < NT; ++t){
    const char* Ab = (const char*)&u.stage[t & 1][0][0];
    const char* Bb = (const char*)&u.stage[t & 1][1][0];
    bf16x8 af[2][4], bq[2][2];
#pragma unroll
    for (int kk = 0; kk < 2; ++kk){
      const int kb = kk*64 + ((lane >> 4) << 4);
#pragma unroll
      for (int i = 0; i < 4; ++i){
        int row = wr*64 + i*16 + (lane & 15);
        af[kk][i] = *(const bf16x8*)(Ab + ((row*128 + kb) ^ ((row & 7) << 4)));
      }
#pragma unroll
      for (int j = 0; j < 2; ++j){
        int col = wc*32 + j*16 + (lane & 15);
        bq[kk][j] = *(const bf16x8*)(Bb + ((col*128 + kb) ^ ((col & 7) << 4)));
      }
    }
    if (t + 2 < NT){
      asm volatile("s_barrier" ::: "memory");
      STAGE(t & 1, t + 2);
    }
#pragma unroll
    for (int kk = 0; kk < 2; ++kk)
#pragma unroll
      for (int i = 0; i < 4; ++i)
#pragma unroll
        for (int j = 0; j < 2; ++j)
          acc[i][j] = __builtin_amdgcn_mfma_f32_16x16x32_bf16(af[kk][i], bq[kk][j], acc[i][j], 0, 0, 0);
    if (t + 1 < NT){
      if (t + 2 < NT) asm volatile("s_waitcnt vmcnt(4)" ::: "memory");
      else            asm volatile("s_waitcnt vmcnt(0)" ::: "memory");
      asm volatile("s_barrier" ::: "memory");
    }
  }

  __syncthreads();
  if (OUT_BF16){
#pragma unroll
    for (int j = 0; j < 2; ++j){
      int cl = wc*32 + j*16 + (lane & 15);
      float bs = bias[col0 + cl];
#pragma unroll
      for (int i = 0; i < 4; ++i){
        int rb = wr*64 + i*16 + ((lane >> 4) << 2);
#pragma unroll
        for (int r = 0; r < 4; ++r){
          float v = acc[i][j][r] + bs;
          if (RELU) v = fmaxf(v, 0.f);
          u.sc16[(rb + r)*136 + cl] = f2bf(v);
        }
      }
    }
    __syncthreads();
    unsigned short* Cb = (unsigned short*)Cv;
    for (int idx = tid; idx < 128*16; idx += 512){
      int rr = idx >> 4, seg = idx & 15;
      int grow = row0 + rr;
      if (grow < M){
        uint4 vv = *(const uint4*)&u.sc16[rr*136 + seg*8];
        *(uint4*)(Cb + (size_t)grow*ldc + col0 + seg*8) = vv;
      }
    }
  } else {
#pragma unroll
    for (int j = 0; j < 2; ++j){
      int cl = wc*32 + j*16 + (lane & 15);
      float bs = bias[col0 + cl];
#pragma unroll
      for (int i = 0; i < 4; ++i){
        int rb = wr*64 + i*16 + ((lane >> 4) << 2);
#pragma unroll
        for (int r = 0; r < 4; ++r){
          float v = acc[i][j][r] + bs;
          if (RELU) v = fmaxf(v, 0.f);
          u.sc32[(rb + r)*132 + cl] = v;
        }
      }
    }
    __syncthreads();
    float* Cf = (float*)Cv;
    for (int idx = tid; idx < 128*32; idx += 512){
      int rr = idx >> 5, seg = idx & 31;
      int grow = row0 + rr;
      if (grow < M){
        float4 vv = *(const float4*)&u.sc32[rr*132 + seg*4];
        *(float4*)(Cf + (size_t)grow*ldc + col0 + seg*4) = vv;
      }
    }
  }
}

// ------- fused GIN-aggregate + conv GEMM1 + deterministic block stats -------
// B fragments read directly from global (L2-hot) — LDS holds only the A tile
// + epilogue scratch (~37 KB) => up to 4 blocks/CU for gather latency hiding.
template<bool IN_BF16>
__global__ __launch_bounds__(512) void k_mmca(
    const void* __restrict__ hin, int ldh,
    const int* __restrict__ rowptr, const int* __restrict__ colsrc,
    const float* __restrict__ epsp,
    const unsigned short* __restrict__ Bt,    // [128][128] bf16, n-major
    const float* __restrict__ bias,
    unsigned short* __restrict__ C, int ldc,
    float* __restrict__ pa,
    int M)
{
  __shared__ unsigned short shm[128*136];     // As (first 32 KB) / epilogue scratch
  __shared__ float sbs[2][128], sbq[2][128];
  unsigned short* As = shm;
  const int tid  = threadIdx.x;
  const int lane = tid & 63;
  const int w    = tid >> 6;
  const int wr   = w >> 2, wc = w & 3;

  const int wg   = xcd_swz(blockIdx.x, gridDim.x);
  const int row0 = wg * 128;

  // gather A: thread handles row r = tid>>2, 32 cols at c0 = (tid&3)*32
  {
    int r  = tid >> 2;
    int c0 = (tid & 3) << 5;
    int node = row0 + r; if (node > M-1) node = M-1;
    float ep = 1.0f + *epsp;
    float a[32];
    if (IN_BF16){
      const unsigned short* src = (const unsigned short*)hin + (size_t)node*ldh + c0;
      uint4 v0 = *(const uint4*)(src);
      uint4 v1 = *(const uint4*)(src + 8);
      uint4 v2 = *(const uint4*)(src + 16);
      uint4 v3 = *(const uint4*)(src + 24);
#pragma unroll
      for (int q = 0; q < 32; ++q) a[q] = 0.f;
      add8(a,      v0); add8(a + 8,  v1); add8(a + 16, v2); add8(a + 24, v3);
#pragma unroll
      for (int q = 0; q < 32; ++q) a[q] *= ep;
    } else {
      const float* src = (const float*)hin + (size_t)node*ldh + c0;
#pragma unroll
      for (int q = 0; q < 32; q += 4){
        float4 f = *(const float4*)(src + q);
        a[q] = ep*f.x; a[q+1] = ep*f.y; a[q+2] = ep*f.z; a[q+3] = ep*f.w;
      }
    }
    int e = rowptr[node], e1 = rowptr[node+1];
    if (IN_BF16){
      for (; e + 2 <= e1; e += 2){            // 2 edges in flight (8 x 16B loads)
        int s0 = colsrc[e], s1 = colsrc[e+1];
        const unsigned short* p0 = (const unsigned short*)hin + (size_t)s0*ldh + c0;
        const unsigned short* p1 = (const unsigned short*)hin + (size_t)s1*ldh + c0;
        uint4 w0 = *(const uint4*)(p0);
        uint4 w1 = *(const uint4*)(p0 + 8);
        uint4 w2 = *(const uint4*)(p0 + 16);
        uint4 w3 = *(const uint4*)(p0 + 24);
        uint4 y0 = *(const uint4*)(p1);
        uint4 y1 = *(const uint4*)(p1 + 8);
        uint4 y2 = *(const uint4*)(p1 + 16);
        uint4 y3 = *(const uint4*)(p1 + 24);
        add8(a,      w0); add8(a + 8,  w1); add8(a + 16, w2); add8(a + 24, w3);
        add8(a,      y0); add8(a + 8,  y1); add8(a + 16, y2); add8(a + 24, y3);
      }
      for (; e < e1; ++e){
        int s = colsrc[e];
        const unsigned short* p = (const unsigned short*)hin + (size_t)s*ldh + c0;
        uint4 w0 = *(const uint4*)(p);
        uint4 w1 = *(const uint4*)(p + 8);
        uint4 w2 = *(const uint4*)(p + 16);
        uint4 w3 = *(const uint4*)(p + 24);
        add8(a,      w0); add8(a + 8,  w1); add8(a + 16, w2); add8(a + 24, w3);
      }
    } else {
      for (; e < e1; ++e){
        int s = colsrc[e];
        const float* p = (const float*)hin + (size_t)s*ldh + c0;
#pragma unroll
        for (int q = 0; q < 32; q += 4){
          float4 f = *(const float4*)(p + q);
          a[q] += f.x; a[q+1] += f.y; a[q+2] += f.z; a[q+3] += f.w;
        }
      }
    }
    // write 32 bf16 (64 B = 4 swizzled 16-B chunks) into As
#pragma unroll
    for (int q = 0; q < 4; ++q){
      unsigned pk[4];
#pragma unroll
      for (int k = 0; k < 4; ++k)
        pk[k] = (unsigned)f2bf(a[q*8 + 2*k]) | ((unsigned)f2bf(a[q*8 + 2*k + 1]) << 16);
      int byte = (r*256 + (tid & 3)*64 + q*16) ^ ((r & 15) << 4);
      *(uint4*)((char*)As + byte) = *(uint4*)pk;
    }
  }

  __syncthreads();

  f32x4 acc[4][2];
#pragma unroll
  for (int i = 0; i < 4; ++i)
#pragma unroll
    for (int j = 0; j < 2; ++j)
      acc[i][j] = (f32x4){0.f, 0.f, 0.f, 0.f};

#pragma unroll
  for (int kk = 0; kk < 4; ++kk){
    const int kb = kk*64 + ((lane >> 4) << 4);
    const int ke = kk*32 + ((lane >> 4) << 3);     // element offset in B row
    bf16x8 af[4], bfr[2];
#pragma unroll
    for (int i = 0; i < 4; ++i){
      int row = wr*64 + i*16 + (lane & 15);
      af[i] = *(const bf16x8*)((const char*)As + ((row*256 + kb) ^ ((row & 15) << 4)));
    }
#pragma unroll
    for (int j = 0; j < 2; ++j){
      int col = wc*32 + j*16 + (lane & 15);
      bfr[j] = *(const bf16x8*)(Bt + (size_t)col*H + ke);
    }
#pragma unroll
    for (int i = 0; i < 4; ++i)
#pragma unroll
      for (int j = 0; j < 2; ++j)
        acc[i][j] = __builtin_amdgcn_mfma_f32_16x16x32_bf16(af[i], bfr[j], acc[i][j], 0, 0, 0);
  }

  // deterministic block stats: wave partials -> LDS -> single combine -> pa
#pragma unroll
  for (int j = 0; j < 2; ++j){
    int col = wc*32 + j*16 + (lane & 15);
    float bs = bias[col];
    float s = 0.f, q = 0.f;
#pragma unroll
    for (int i = 0; i < 4; ++i){
      int rb = row0 + wr*64 + i*16 + ((lane >> 4) << 2);
#pragma unroll
      for (int r = 0; r < 4; ++r){
        if (rb + r < M){
          float v = acc[i][j][r] + bs;
          s += v; q += v*v;
        }
      }
    }
    s += __shfl_xor(s, 16); q += __shfl_xor(q, 16);
    s += __shfl_xor(s, 32); q += __shfl_xor(q, 32);
    if (lane < 16){ sbs[wr][col] = s; sbq[wr][col] = q; }
  }
  __syncthreads();
  if (tid < 128){
    pa[(size_t)wg*256 + tid]       = sbs[0][tid] + sbs[1][tid];
    pa[(size_t)wg*256 + 128 + tid] = sbq[0][tid] + sbq[1][tid];
  }

  // epilogue: transpose via LDS (A tile dead), coalesced 16-B stores
  __syncthreads();
#pragma unroll
  for (int j = 0; j < 2; ++j){
    int cl = wc*32 + j*16 + (lane & 15);
    float bs = bias[cl];
#pragma unroll
    for (int i = 0; i < 4; ++i){
      int rb = wr*64 + i*16 + ((lane >> 4) << 2);
#pragma unroll
      for (int r = 0; r < 4; ++r)
        shm[(rb + r)*136 + cl] = f2bf(acc[i][j][r] + bs);
    }
  }
  __syncthreads();
  for (int idx = tid; idx < 128*16; idx += 512){
    int rr = idx >> 4, seg = idx & 15;
    int grow = row0 + rr;
    if (grow < M){
      uint4 vv = *(const uint4*)&shm[rr*136 + seg*8];
      *(uint4*)(C + (size_t)grow*ldc + seg*8) = vv;
    }
  }
}

// ------- conv GEMM2: BN1 from global scale/shift; B frags direct from global -------
__global__ __launch_bounds__(512) void k_mmc2(
    const unsigned short* __restrict__ A,     // [M][128] bf16 (pre-BN1)
    const unsigned short* __restrict__ Bt,
    const float* __restrict__ bias,
    const float* __restrict__ sc1, const float* __restrict__ sf1,  // BN1 scale/shift
    unsigned short* __restrict__ C, int ldc,
    float* __restrict__ pb,                   // [nwg][256] BN2 partials
    int M)
{
  __shared__ unsigned short shm[128*136];     // As (first 32 KB) / epilogue scratch
  __shared__ float bnsc[128], bnsf[128];
  __shared__ float rs[2][128], rq[2][128];
  unsigned short* As = shm;
  const int tid  = threadIdx.x;
  const int lane = tid & 63;
  const int w    = tid >> 6;
  const int wr   = w >> 2, wc = w & 3;
  const int nwg  = gridDim.x;

  const int wg   = xcd_swz(blockIdx.x, nwg);
  const int row0 = wg * 128;

#pragma unroll
  for (int j = 0; j < 4; ++j){
    int d = w*4096 + j*1024 + lane*16;
    int m = d >> 8;
    int inner = (d & 255) ^ ((m & 15) << 4);
    int gm = row0 + m; if (gm > M-1) gm = M-1;
    __builtin_amdgcn_global_load_lds(
        (const __attribute__((address_space(1))) void*)(A + (size_t)gm*H + (inner >> 1)),
        (__attribute__((address_space(3))) void*)((char*)As + w*4096 + j*1024),
        16, 0, 0);
  }

  // BN1 scale/shift: plain load (overlaps with staging)
  if (tid < 128){
    bnsc[tid] = sc1[tid];
    bnsf[tid] = sf1[tid];
  }

  asm volatile("s_waitcnt vmcnt(0)" ::: "memory");
  __syncthreads();

  f32x4 acc[4][2];
#pragma unroll
  for (int i = 0; i < 4; ++i)
#pragma unroll
    for (int j = 0; j < 2; ++j)
      acc[i][j] = (f32x4){0.f, 0.f, 0.f, 0.f};

#pragma unroll
  for (int kk = 0; kk < 4; ++kk){
    const int kb = kk*64 + ((lane >> 4) << 4);
    const int ke = kk*32 + ((lane >> 4) << 3);
    bf16x8 af[4], bfr[2];
#pragma unroll
    for (int i = 0; i < 4; ++i){
      int row = wr*64 + i*16 + (lane & 15);
      af[i] = *(const bf16x8*)((const char*)As + ((row*256 + kb) ^ ((row & 15) << 4)));
    }
#pragma unroll
    for (int j = 0; j < 2; ++j){
      int col = wc*32 + j*16 + (lane & 15);
      bfr[j] = *(const bf16x8*)(Bt + (size_t)col*H + ke);
    }
    {
      int k8 = kk*32 + ((lane >> 4) << 3);
      float4 s0 = *(const float4*)(&bnsc[k8]), s1 = *(const float4*)(&bnsc[k8 + 4]);
      float4 f0 = *(const float4*)(&bnsf[k8]), f1 = *(const float4*)(&bnsf[k8 + 4]);
      float sc[8] = {s0.x,s0.y,s0.z,s0.w,s1.x,s1.y,s1.z,s1.w};
      float sf[8] = {f0.x,f0.y,f0.z,f0.w,f1.x,f1.y,f1.z,f1.w};
#pragma unroll
      for (int i = 0; i < 4; ++i){
        bf16x8 aa = af[i], o;
#pragma unroll
        for (int jj = 0; jj < 8; ++jj){
          float v = fmaxf(fmaf(sc[jj], bf2f((unsigned short)aa[jj]), sf[jj]), 0.f);
          o[jj] = (short)f2bf(v);
        }
        af[i] = o;
      }
    }
#pragma unroll
    for (int i = 0; i < 4; ++i)
#pragma unroll
      for (int j = 0; j < 2; ++j)
        acc[i][j] = __builtin_amdgcn_mfma_f32_16x16x32_bf16(af[i], bfr[j], acc[i][j], 0, 0, 0);
  }

  // deterministic block stats -> pb
#pragma unroll
  for (int j = 0; j < 2; ++j){
    int col = wc*32 + j*16 + (lane & 15);
    float bs = bias[col];
    float s = 0.f, q = 0.f;
#pragma unroll
    for (int i = 0; i < 4; ++i){
      int rb = row0 + wr*64 + i*16 + ((lane >> 4) << 2);
#pragma unroll
      for (int r = 0; r < 4; ++r){
        if (rb + r < M){
          float v = acc[i][j][r] + bs;
          s += v; q += v*v;
        }
      }
    }
    s += __shfl_xor(s, 16); q += __shfl_xor(q, 16);
    s += __shfl_xor(s, 32); q += __shfl_xor(q, 32);
    if (lane < 16){ rs[wr][col] = s; rq[wr][col] = q; }
  }
  __syncthreads();
  if (tid < 128){
    pb[(size_t)wg*256 + tid]       = rs[0][tid] + rs[1][tid];
    pb[(size_t)wg*256 + 128 + tid] = rq[0][tid] + rq[1][tid];
  }

  __syncthreads();
#pragma unroll
  for (int j = 0; j < 2; ++j){
    int cl = wc*32 + j*16 + (lane & 15);
    float bs = bias[cl];
#pragma unroll
    for (int i = 0; i < 4; ++i){
      int rb = wr*64 + i*16 + ((lane >> 4) << 2);
#pragma unroll
      for (int r = 0; r < 4; ++r)
        shm[(rb + r)*136 + cl] = f2bf(acc[i][j][r] + bs);
    }
  }
  __syncthreads();
  for (int idx = tid; idx < 128*16; idx += 512){
    int rr = idx >> 4, seg = idx & 15;
    int grow = row0 + rr;
    if (grow < M){
      uint4 vv = *(const uint4*)&shm[rr*136 + seg*8];
      *(uint4*)(C + (size_t)grow*ldc + seg*8) = vv;
    }
  }
}

// ---- BN finalize: one block per channel, fixed-tree deterministic reduction ----
__global__ __launch_bounds__(128) void k_bnfin2(const float* __restrict__ pp,
                                                const float* __restrict__ g,
                                                const float* __restrict__ b,
                                                float* __restrict__ scale,
                                                float* __restrict__ shift,
                                                float invn, int nwg){
  __shared__ float ss[128], qq[128];
  int c = blockIdx.x;      // channel 0..127
  int j = threadIdx.x;     // 0..127
  float s = 0.f, q = 0.f;
  for (int bi = j; bi < nwg; bi += 128){
    s += pp[(size_t)bi*256 + c];
    q += pp[(size_t)bi*256 + 128 + c];
  }
  ss[j] = s; qq[j] = q;
  __syncthreads();
#pragma unroll
  for (int off = 64; off > 0; off >>= 1){
    if (j < off){ ss[j] += ss[j+off]; qq[j] += qq[j+off]; }
    __syncthreads();
  }
  if (j == 0){
    float m = ss[0]*invn;
    float v = qq[0]*invn - m*m;
    float inv = rsqrtf(v + BN_EPS);
    float sc = g[c]*inv;
    scale[c] = sc;
    shift[c] = b[c] - m*sc;
  }
}

// ---- BN2 apply: out = bf16(relu(sc*U+sf)), U stride ldu ----
__global__ __launch_bounds__(256) void k_bnapply(const unsigned short* __restrict__ U,
                                                 int ldu,
                                                 const float* __restrict__ scale,
                                                 const float* __restrict__ shift,
                                                 unsigned short* __restrict__ out,
                                                 int ldo, int n){
  int i = blockIdx.x*256 + threadIdx.x;
  int total = n * (H/4);
  if (i < total){
    int r = i >> 5;
    int c4 = (i & 31) << 2;
    uint2 up = *(const uint2*)(U + (size_t)r*ldu + c4);
    float4 sc = *(const float4*)(scale + c4);
    float4 sf = *(const float4*)(shift + c4);
    float a = fmaxf(fmaf(sc.x, bf2f((unsigned short)up.x),       sf.x), 0.f);
    float c = fmaxf(fmaf(sc.y, bf2f((unsigned short)(up.x>>16)), sf.y), 0.f);
    float d = fmaxf(fmaf(sc.z, bf2f((unsigned short)up.y),       sf.z), 0.f);
    float e = fmaxf(fmaf(sc.w, bf2f((unsigned short)(up.y>>16)), sf.w), 0.f);
    uint2 o;
    o.x = (unsigned)f2bf(a) | ((unsigned)f2bf(c) << 16);
    o.y = (unsigned)f2bf(d) | ((unsigned)f2bf(e) << 16);
    *(uint2*)(out + (size_t)r*ldo + c4) = o;
  }
}

// ---------------- f32 GEMM 32x64 tile (graph FF, M=512) ----------------
template<bool RELU, bool ADD_D>
__global__ __launch_bounds__(256) void k_gemm64(
    const float* __restrict__ A, int lda,
    const float* __restrict__ B, int ldb,
    const float* __restrict__ bias,
    const float* D, int ldd,
    float* C, int ldc,
    int M, int N, int K)
{
  __shared__ float As[32][36];
  __shared__ float Bs[32][64];
  const int tid  = threadIdx.x;
  const int tx   = tid & 15;
  const int ty   = tid >> 4;
  const int row0 = blockIdx.x * 32;
  const int col0 = blockIdx.y * 64;
  const int am = tid >> 3;
  const int ak = (tid & 7) << 2;
  const int bk = tid >> 4;
  const int bn = (tid & 15) << 2;
  float acc[2][4] = {};

  for (int k0 = 0; k0 < K; k0 += 32){
    {
      int gr = row0 + am;
      float4 v = make_float4(0.f, 0.f, 0.f, 0.f);
      if (gr < M) v = *(const float4*)(A + (size_t)gr*lda + k0 + ak);
      As[ak+0][am]=v.x; As[ak+1][am]=v.y; As[ak+2][am]=v.z; As[ak+3][am]=v.w;
    }
#pragma unroll
    for (int h = 0; h < 2; ++h){
      int kk = bk + h*16;
      *(float4*)(&Bs[kk][bn]) = *(const float4*)(B + (size_t)(k0+kk)*ldb + col0 + bn);
    }
    __syncthreads();
#pragma unroll 8
    for (int k = 0; k < 32; ++k){
      float2 a = *(const float2*)(&As[k][ty<<1]);
      float4 b = *(const float4*)(&Bs[k][tx<<2]);
      float av[2] = {a.x, a.y};
      float bv[4] = {b.x, b.y, b.z, b.w};
#pragma unroll
      for (int i = 0; i < 2; ++i)
#pragma unroll
        for (int j = 0; j < 4; ++j)
          acc[i][j] = fmaf(av[i], bv[j], acc[i][j]);
    }
    __syncthreads();
  }

  const int col = col0 + (tx<<2);
  float4 bv = *(const float4*)(bias + col);
#pragma unroll
  for (int i = 0; i < 2; ++i){
    int row = row0 + (ty<<1) + i;
    if (row < M){
      float r[4] = {acc[i][0]+bv.x, acc[i][1]+bv.y, acc[i][2]+bv.z, acc[i][3]+bv.w};
      if (RELU){
#pragma unroll
        for (int j = 0; j < 4; ++j) r[j] = fmaxf(r[j], 0.f);
      }
      if (ADD_D){
        float4 d = *(const float4*)(D + (size_t)row*ldd + col);
        r[0]+=d.x; r[1]+=d.y; r[2]+=d.z; r[3]+=d.w;
      }
      *(float4*)(C + (size_t)row*ldc + col) = make_float4(r[0],r[1],r[2],r[3]);
    }
  }
}

// ---------------- host ----------------
extern "C" void kernel_launch(void* const* d_in, const int* in_sizes, int n_in,
                              void* d_out, int out_size, void* d_ws, size_t ws_size,
                              hipStream_t stream) {
  const float* x        = (const float*)d_in[0];
  const int*   ei       = (const int*)d_in[1];
  const int*   batch    = (const int*)d_in[2];
  const float* conv_W1  = (const float*)d_in[3];
  const float* conv_b1  = (const float*)d_in[4];
  const float* conv_g1  = (const float*)d_in[5];
  const float* conv_be1 = (const float*)d_in[6];
  const float* conv_W2  = (const float*)d_in[7];
  const float* conv_b2  = (const float*)d_in[8];
  const float* epsv     = (const float*)d_in[9];
  const float* bn_g     = (const float*)d_in[10];
  const float* bn_b     = (const float*)d_in[11];
  const float* pred_W   = (const float*)d_in[12];
  const float* pred_b   = (const float*)d_in[13];
  const float* gW       = (const float*)d_in[14];
  const float* gb       = (const float*)d_in[15];
  const float* gsW      = (const float*)d_in[16];
  const float* gsb      = (const float*)d_in[17];
  const float* lW       = (const float*)d_in[18];
  const float* lb       = (const float*)d_in[19];
  const float* lsW      = (const float*)d_in[20];
  const float* lsb      = (const float*)d_in[21];

  const int N = in_sizes[0] / H;
  const int E = in_sizes[1] / 2;
  const int* srcI = ei;
  const int* dstI = ei + E;

  float* out = (float*)d_out;
  float* GE = out;                              // [NG][EMB]
  float* NE = out + (size_t)NG*EMB;             // [N][EMB] f32
  float* XC = NE + (size_t)N*EMB;               // [NG][EMB]

  // ---- workspace layout ----
  unsigned short* xall = (unsigned short*)d_ws;             // [N][EMB] bf16 (post-BN2)
  unsigned short* h1   = xall + (size_t)N*EMB;              // [N][EMB] bf16
  unsigned short* h2   = h1 + (size_t)N*EMB;                // [N][EMB] bf16
  unsigned short* ub   = h1;                                // [N][H] (alias, conv loop)
  unsigned short* xpre = h2;                                // [N][EMB] pre-BN2 (h2 reused after pool)

  float* pooled  = (float*)(h2 + (size_t)N*EMB);            // [NG][EMB]
  float* gtmp1   = pooled + (size_t)NG*EMB;
  float* gtmp2   = gtmp1 + (size_t)NG*EMB;
  const int nrow = (N + 127)/128;                           // 391
  float* pa      = gtmp2 + (size_t)NG*EMB;                  // [nrow][256] BN1 partials
  float* pb      = pa + (size_t)nrow*256;                   // [nrow][256] BN2 partials
  float* bnsc2   = pb + (size_t)nrow*256;                   // [5][128]
  float* bnsf2   = bnsc2 + LNUM*128;                        // [5][128]
  float* bnsc1   = bnsf2 + LNUM*128;                        // [128]
  float* bnsf1   = bnsc1 + 128;                             // [128]
  float* biasNE  = bnsf1 + 128;                             // [640]
  unsigned short* W1t   = (unsigned short*)(biasNE + EMB);  // [L][H][H]
  unsigned short* W2t   = W1t + (size_t)LNUM*H*H;
  unsigned short* lWt01 = W2t + (size_t)LNUM*H*H;           // [2][EMB][EMB]
  unsigned short* Wcat  = lWt01 + (size_t)2*EMB*EMB;        // [EMB][2*EMB]
  int* rowptr = (int*)(Wcat + (size_t)2*EMB*EMB);           // [N+1]
  int* cursor = rowptr + (N + 1);                           // [N]
  int* colsrc = cursor + N;                                 // [E]
  int* gstart = colsrc + E;                                 // [NG+1]

  // CSR build (deterministic: segments sorted after scatter)
  k_zeroi<<<(N+255)/256, 256, 0, stream>>>(cursor, N);
  k_hist<<<(E+255)/256, 256, 0, stream>>>(dstI, E, cursor);
  k_scan<<<1, 1024, 0, stream>>>(cursor, rowptr, N);
  k_scatter<<<(E+255)/256, 256, 0, stream>>>(srcI, dstI, E, cursor, colsrc);
  k_sortseg<<<(N+255)/256, 256, 0, stream>>>(rowptr, colsrc, N);
  k_gstart<<<(NG+256)/256, 256, 0, stream>>>(batch, N, gstart);

  // weights -> bf16 transposed [n][k]
  const dim3 tb32(32, 8);
  k_castT<<<dim3(H/32, H/32, LNUM), tb32, 0, stream>>>(conv_W1, W1t, H, H, H, 0);
  k_castT<<<dim3(H/32, H/32, LNUM), tb32, 0, stream>>>(conv_W2, W2t, H, H, H, 0);
  k_castT<<<dim3(EMB/32, EMB/32, 2), tb32, 0, stream>>>(lW, lWt01, EMB, EMB, EMB, 0);
  k_castT<<<dim3(EMB/32, EMB/32, 1), tb32, 0, stream>>>(lW + (size_t)2*EMB*EMB, Wcat,
                                                        EMB, EMB, 2*EMB, 0);
  k_castT<<<dim3(EMB/32, EMB/32, 1), tb32, 0, stream>>>(lsW, Wcat, EMB, EMB, 2*EMB, EMB);
  k_bias2<<<1, EMB, 0, stream>>>(lb + (size_t)2*EMB, lsb, biasNE);

  const float invn = 1.0f / (float)N;

  for (int l = 0; l < LNUM; ++l){
    // ub = agg(h) @ W1 + b1  (fused gather; bf16 out; BN1 partials -> pa)
    if (l == 0)
      k_mmca<false><<<nrow, 512, 0, stream>>>(
          x, H, rowptr, colsrc, epsv, W1t, conv_b1, ub, H, pa, N);
    else
      k_mmca<true><<<nrow, 512, 0, stream>>>(
          xall + (size_t)(l-1)*H, EMB, rowptr, colsrc, epsv + l,
          W1t + (size_t)l*H*H, conv_b1 + l*H, ub, H, pa, N);

    // BN1 finalize (parallel, deterministic fixed-tree)
    k_bnfin2<<<128, 128, 0, stream>>>(pa, conv_g1 + l*H, conv_be1 + l*H,
                                      bnsc1, bnsf1, invn, nrow);

    // xpre[:,l*H:] = relu(bn1(ub)) @ W2 + b2  (BN2 partials -> pb)
    k_mmc2<<<nrow, 512, 0, stream>>>(
        ub, W2t + (size_t)l*H*H, conv_b2 + l*H,
        bnsc1, bnsf1,
        xpre + (size_t)l*H, EMB, pb, N);

    // BN2 finalize -> per-layer scale/shift (parallel, deterministic)
    k_bnfin2<<<128, 128, 0, stream>>>(pb, bn_g + l*H, bn_b + l*H,
                                      bnsc2 + l*128, bnsf2 + l*128, invn, nrow);

    // xall[:,l*H:] = bf16(relu(bn2(xpre)))
    k_bnapply<<<(N*32 + 255)/256, 256, 0, stream>>>(
        xpre + (size_t)l*H, EMB, bnsc2 + l*128, bnsf2 + l*128,
        xall + (size_t)l*H, EMB, N);
  }

  // pooling (BN2 applied in f32 from xpre) + prediction heads -> xcat
  k_pool<<<NG, 320, 0, stream>>>(xpre, bnsc2, bnsf2, gstart, pooled);
  k_pred<<<dim3(NG, LNUM), 128, 0, stream>>>(pooled, pred_W, pred_b, XC);

  // graph FF (f32, M=512): GE = relu-chain(XC) + XC @ gsW + gsb
  const dim3 gg((NG + 31)/32, EMB/64);          // (16, 10)
  k_gemm64<false,false><<<gg, 256, 0, stream>>>(XC, EMB, gsW, EMB, gsb,
                                                nullptr, 0, GE, EMB, NG, EMB, EMB);
  k_gemm64<true,false><<<gg, 256, 0, stream>>>(XC, EMB, gW, EMB, gb,
                                               nullptr, 0, gtmp1, EMB, NG, EMB, EMB);
  k_gemm64<true,false><<<gg, 256, 0, stream>>>(gtmp1, EMB, gW + (size_t)EMB*EMB, EMB, gb + EMB,
                                               nullptr, 0, gtmp2, EMB, NG, EMB, EMB);
  k_gemm64<true,true><<<gg, 256, 0, stream>>>(gtmp2, EMB, gW + (size_t)2*EMB*EMB, EMB, gb + 2*EMB,
                                              GE, EMB, GE, EMB, NG, EMB, EMB);

  // node FF (bf16 MFMA, 128x128 tile, depth-2 raw-barrier pipeline, XCD swizzle):
  const dim3 gn(EMB/128, nrow);                 // (5, 391)
  // h1 = relu(xall @ lW0 + lb0)
  k_mm<true,true,false><<<gn, 512, 0, stream>>>(
      xall, EMB, nullptr, lWt01, EMB, lb, h1, EMB, N, EMB);
  // h2 = relu(h1 @ lW1 + lb1)   (h2 aliases xpre — pool already consumed it)
  k_mm<true,true,false><<<gn, 512, 0, stream>>>(
      h1, EMB, nullptr, lWt01 + (size_t)EMB*EMB, EMB, lb + EMB, h2, EMB, N, EMB);
  // NE = [h2 | xall] @ [lW2 ; lsW] + (lb2 + lsb)   (dual-A, K=1280, f32 out)
  k_mm<false,false,true><<<gn, 512, 0, stream>>>(
      h2, EMB, xall, Wcat, 2*EMB, biasNE, NE, EMB, N, 2*EMB);
}